// Round 2
// baseline (619.688 us; speedup 1.0000x reference)
//
#include <hip/hip_runtime.h>
#include <stdint.h>
#include <stddef.h>

typedef short s8v __attribute__((ext_vector_type(8)));   // 8 bf16 (bit pattern in shorts)
typedef float f4  __attribute__((ext_vector_type(4)));
typedef unsigned int u32;

#define SCALE2_ 0.18033688011112042f   /* 0.125 * log2(e) — softmax in exp2 domain */
#define NEG_BIG -3.0e38f

static __device__ __forceinline__ short f2bf(float f) {
    u32 u = __builtin_bit_cast(u32, f);
    u = (u + 0x7fffu + ((u >> 16) & 1u)) >> 16;
    return (short)u;
}

// ---------------- pack / convert kernels ----------------

__global__ __launch_bounds__(256) void k_cvt(const float* __restrict__ in,
                                             s8v* __restrict__ out, int n8) {
    int i = blockIdx.x * 256 + threadIdx.x;
    if (i >= n8) return;
    const float4* p = (const float4*)in;
    float4 a = p[2 * i], b = p[2 * i + 1];
    s8v o;
    o[0] = f2bf(a.x); o[1] = f2bf(a.y); o[2] = f2bf(a.z); o[3] = f2bf(a.w);
    o[4] = f2bf(b.x); o[5] = f2bf(b.y); o[6] = f2bf(b.z); o[7] = f2bf(b.w);
    out[i] = o;
}

// Wq/Wk/Wv: (16,1024,64) each -> Wqkv_bt[n][d], n = p*1024 + h*64 + k  (B^T form, N x K)
__global__ __launch_bounds__(256) void k_pack_wqkv(const float* __restrict__ Wq,
                                                   const float* __restrict__ Wk,
                                                   const float* __restrict__ Wv,
                                                   s8v* __restrict__ out) {
    int idx = blockIdx.x * 256 + threadIdx.x;   // 3072*128 threads
    int n = idx >> 7, d8 = idx & 127;
    const float* W = (n < 1024) ? Wq : ((n < 2048) ? Wk : Wv);
    int nn = n & 1023;
    const float* src = W + (size_t)((nn >> 6) * 1024 + d8 * 8) * 64 + (nn & 63);
    s8v o;
    #pragma unroll
    for (int i = 0; i < 8; i++) o[i] = f2bf(src[i * 64]);
    out[idx] = o;
}

__global__ __launch_bounds__(256) void k_pack_bias(const float* __restrict__ bq,
                                                   const float* __restrict__ bk,
                                                   const float* __restrict__ bv,
                                                   float* __restrict__ o) {
    int n = blockIdx.x * 256 + threadIdx.x;
    if (n >= 3072) return;
    const float* b = (n < 1024) ? bq : ((n < 2048) ? bk : bv);
    o[n] = b[n & 1023];
}

// ---------------- GEMM: C = A(MxK) * Bt(NxK)^T, bf16 in, custom epilogue ----------------
// EPI=0: QKV projection -> scatter bf16 into Q[bh][t][k], K[bh][t][k], V^T[bh][v][t]
// EPI=1: output projection -> fp32 out = (acc + bout[n]) * drop[m][n]

template <int EPI>
__global__ __launch_bounds__(256) void gemm_bt(
    const short* __restrict__ A, const short* __restrict__ Bt,
    int M, int N, int K,
    const float* __restrict__ bias,
    const float* __restrict__ drop, float* __restrict__ outf,
    short* __restrict__ outq, short* __restrict__ outk, short* __restrict__ outv)
{
    __shared__ short lA[128 * 64];
    __shared__ short lB[128 * 64];
    const int tid = threadIdx.x;
    const int w = tid >> 6, l = tid & 63;
    const int wm = w >> 1, wn = w & 1;
    const int lr = l & 15, lg = l >> 4;
    const int bm = blockIdx.y * 128, bn = blockIdx.x * 128;

    f4 acc[4][4] = {};

    const short* Ab = A + (size_t)bm * K + (size_t)(l >> 3) * K + (l & 7) * 8;
    const short* Bb = Bt + (size_t)bn * K + (size_t)(l >> 3) * K + (l & 7) * 8;

    const int nk = K >> 6;
    for (int ks = 0; ks < nk; ks++) {
        const size_t koff = (size_t)ks * 64;
        #pragma unroll
        for (int i = 0; i < 4; i++) {
            const int rr = (i * 4 + w) * 8;
            __builtin_amdgcn_global_load_lds(
                (const __attribute__((address_space(1))) void*)(Ab + (size_t)rr * K + koff),
                (__attribute__((address_space(3))) void*)(&lA[rr * 64]), 16, 0, 0);
            __builtin_amdgcn_global_load_lds(
                (const __attribute__((address_space(1))) void*)(Bb + (size_t)rr * K + koff),
                (__attribute__((address_space(3))) void*)(&lB[rr * 64]), 16, 0, 0);
        }
        __syncthreads();
        #pragma unroll
        for (int c = 0; c < 2; c++) {
            s8v af[4], bfv[4];
            #pragma unroll
            for (int mt = 0; mt < 4; mt++)
                af[mt] = *(const s8v*)&lA[(wm * 64 + mt * 16 + lr) * 64 + c * 32 + lg * 8];
            #pragma unroll
            for (int nt = 0; nt < 4; nt++)
                bfv[nt] = *(const s8v*)&lB[(wn * 64 + nt * 16 + lr) * 64 + c * 32 + lg * 8];
            #pragma unroll
            for (int mt = 0; mt < 4; mt++)
                #pragma unroll
                for (int nt = 0; nt < 4; nt++)
                    acc[mt][nt] = __builtin_amdgcn_mfma_f32_16x16x32_bf16(
                        af[mt], bfv[nt], acc[mt][nt], 0, 0, 0);
        }
        __syncthreads();
    }

    #pragma unroll
    for (int mt = 0; mt < 4; mt++) {
        #pragma unroll
        for (int nt = 0; nt < 4; nt++) {
            const int n = bn + wn * 64 + nt * 16 + lr;
            const float bb = bias[n];
            #pragma unroll
            for (int j = 0; j < 4; j++) {
                const int m = bm + wm * 64 + mt * 16 + lg * 4 + j;
                const float v = acc[mt][nt][j] + bb;
                if (EPI == 0) {
                    const int p = n >> 10, hh = (n >> 6) & 15, kk = n & 63;
                    const int b = m >> 11, t = m & 2047;
                    const size_t bh = (size_t)(b * 16 + hh);
                    if (p == 0)      outq[(bh * 2048 + t) * 64 + kk] = f2bf(v);
                    else if (p == 1) outk[(bh * 2048 + t) * 64 + kk] = f2bf(v);
                    else             outv[bh * 131072 + (size_t)kk * 2048 + t] = f2bf(v); // V^T
                } else {
                    const size_t off = (size_t)m * N + n;
                    outf[off] = v * drop[off];
                }
            }
        }
    }
}

// ---------------- flash attention (causal) ----------------
// Q,K: bf16 [bh][t][64]. Vt: bf16 [bh][v][t] (pre-transposed). Ctx: bf16 [bh][t][64].
// Block: 4 INDEPENDENT waves (no barriers), wave w owns q rows qb*64+w*16..+15.
// Swapped QK^T: accs = K * Q^T -> row=key, col=q. PV: acc_o = V^T * P^T -> row=v, col=q.

__global__ __launch_bounds__(256) void attn_fwd(
    const short* __restrict__ Q, const short* __restrict__ Kv,
    const short* __restrict__ Vt, short* __restrict__ Ctx)
{
    const int bh = blockIdx.y;
    const int qb = (int)gridDim.x - 1 - (int)blockIdx.x;   // big tiles first
    const int tid = threadIdx.x, w = tid >> 6, l = tid & 63;
    const int lr = l & 15, lg = l >> 4;

    __shared__ short Pl[4][16][72];     // per-wave P: [q][key], padded

    const size_t base = (size_t)bh * 131072;
    const int qt0 = qb * 64 + w * 16;
    const int qrow = qt0 + lr;

    const s8v q0 = *(const s8v*)&Q[base + (size_t)(qt0 + lr) * 64 + lg * 8];
    const s8v q1 = *(const s8v*)&Q[base + (size_t)(qt0 + lr) * 64 + 32 + lg * 8];

    f4 acc_o[4] = {};
    float m_run = NEG_BIG, l_run = 0.f;

    for (int j = 0; j <= qb; j++) {
        // S^T = K * Q^T  (K frags from global; L2-resident)
        f4 accs[4] = {};
        #pragma unroll
        for (int kt = 0; kt < 4; kt++) {
            const short* kp = &Kv[base + (size_t)(j * 64 + kt * 16 + lr) * 64 + lg * 8];
            const s8v k0 = *(const s8v*)kp;
            const s8v k1 = *(const s8v*)(kp + 32);
            accs[kt] = __builtin_amdgcn_mfma_f32_16x16x32_bf16(k0, q0, accs[kt], 0, 0, 0);
            accs[kt] = __builtin_amdgcn_mfma_f32_16x16x32_bf16(k1, q1, accs[kt], 0, 0, 0);
        }

        // prefetch V^T fragments (independent of accs -> overlaps softmax)
        s8v vf[2][4];
        #pragma unroll
        for (int c = 0; c < 2; c++)
            #pragma unroll
            for (int vt = 0; vt < 4; vt++)
                vf[c][vt] = *(const s8v*)&Vt[base + (size_t)(vt * 16 + lr) * 2048
                                             + j * 64 + c * 32 + lg * 8];

        // scale + causal mask (exp2 domain)
        float pm = NEG_BIG;
        #pragma unroll
        for (int kt = 0; kt < 4; kt++)
            #pragma unroll
            for (int r = 0; r < 4; r++) {
                const int key = j * 64 + kt * 16 + lg * 4 + r;
                float vv = accs[kt][r] * SCALE2_;
                vv = (key > qrow) ? NEG_BIG : vv;
                accs[kt][r] = vv;
                pm = fmaxf(pm, vv);
            }
        pm = fmaxf(pm, __shfl_xor(pm, 16));
        pm = fmaxf(pm, __shfl_xor(pm, 32));

        // defer-max: only rescale when the running max actually grows (T13, THR=8)
        if (!__all(pm <= m_run + 8.f)) {
            const float m_new = fmaxf(m_run, pm);
            const float so = exp2f(m_run - m_new);
            l_run *= so;
            #pragma unroll
            for (int vt = 0; vt < 4; vt++) {
                acc_o[vt][0] *= so; acc_o[vt][1] *= so;
                acc_o[vt][2] *= so; acc_o[vt][3] *= so;
            }
            m_run = m_new;
        }

        // exp + row-sum + pack P -> per-wave LDS [q][key]
        float ps = 0.f;
        #pragma unroll
        for (int kt = 0; kt < 4; kt++) {
            const float e0 = exp2f(accs[kt][0] - m_run);
            const float e1 = exp2f(accs[kt][1] - m_run);
            const float e2 = exp2f(accs[kt][2] - m_run);
            const float e3 = exp2f(accs[kt][3] - m_run);
            ps += (e0 + e1) + (e2 + e3);
            short4 pk;
            pk.x = f2bf(e0); pk.y = f2bf(e1); pk.z = f2bf(e2); pk.w = f2bf(e3);
            *(short4*)&Pl[w][lr][kt * 16 + lg * 4] = pk;
        }
        ps += __shfl_xor(ps, 16);
        ps += __shfl_xor(ps, 32);
        l_run += ps;

        // O^T += V^T * P^T   (wave-synchronous LDS read of P)
        #pragma unroll
        for (int c = 0; c < 2; c++) {
            const s8v pf = *(const s8v*)&Pl[w][lr][c * 32 + lg * 8];
            #pragma unroll
            for (int vt = 0; vt < 4; vt++)
                acc_o[vt] = __builtin_amdgcn_mfma_f32_16x16x32_bf16(
                    vf[c][vt], pf, acc_o[vt], 0, 0, 0);
        }
    }

    // epilogue: normalize, transpose via per-wave LDS, coalesced bf16 store
    const float inv = 1.f / l_run;
    #pragma unroll
    for (int vt = 0; vt < 4; vt++) {
        short4 ob;
        ob.x = f2bf(acc_o[vt][0] * inv);
        ob.y = f2bf(acc_o[vt][1] * inv);
        ob.z = f2bf(acc_o[vt][2] * inv);
        ob.w = f2bf(acc_o[vt][3] * inv);
        *(short4*)&Pl[w][lr][vt * 16 + lg * 4] = ob;
    }
    {
        const int qq = l >> 2;
        const int c0 = (l & 3) * 16;
        const s8v o0 = *(const s8v*)&Pl[w][qq][c0];
        const s8v o1 = *(const s8v*)&Pl[w][qq][c0 + 8];
        short* dst = (short*)&Ctx[base + (size_t)(qt0 + qq) * 64 + c0];
        *(s8v*)dst = o0;
        *(s8v*)(dst + 8) = o1;
    }
}

// ---------------- launch ----------------

#define WS_XB   ((size_t)0)
#define WS_WQKV ((size_t)16777216)
#define WS_WOUT ((size_t)23068672)
#define WS_BQKV ((size_t)25165824)
#define WS_Q    ((size_t)25178112)
#define WS_K    ((size_t)41955328)
#define WS_V    ((size_t)58732544)
#define WS_CTX  ((size_t)75509760)

extern "C" void kernel_launch(void* const* d_in, const int* in_sizes, int n_in,
                              void* d_out, int out_size, void* d_ws, size_t ws_size,
                              hipStream_t stream) {
    const float* x    = (const float*)d_in[0];
    // d_in[1] = attn_mask (causal, hardcoded in attn_fwd)
    const float* Wq   = (const float*)d_in[2];
    const float* bq   = (const float*)d_in[3];
    const float* Wk   = (const float*)d_in[4];
    const float* bk   = (const float*)d_in[5];
    const float* Wv   = (const float*)d_in[6];
    const float* bv   = (const float*)d_in[7];
    const float* Wout = (const float*)d_in[8];
    const float* bout = (const float*)d_in[9];
    const float* drop = (const float*)d_in[10];
    float* out = (float*)d_out;

    char* ws = (char*)d_ws;
    short* Xb    = (short*)(ws + WS_XB);
    short* Wqkvb = (short*)(ws + WS_WQKV);
    short* Woutb = (short*)(ws + WS_WOUT);
    float* bqkv  = (float*)(ws + WS_BQKV);
    short* Qb    = (short*)(ws + WS_Q);
    short* Kb    = (short*)(ws + WS_K);
    short* Vtb   = (short*)(ws + WS_V);     // V stored TRANSPOSED: [bh][v][t]
    short* Ctxb  = (short*)(ws + WS_CTX);

    k_cvt<<<4096, 256, 0, stream>>>(x, (s8v*)Xb, 1048576);          // x -> bf16
    k_cvt<<<512, 256, 0, stream>>>(Wout, (s8v*)Woutb, 131072);      // Wout -> bf16 (already B^T form)
    k_pack_wqkv<<<1536, 256, 0, stream>>>(Wq, Wk, Wv, (s8v*)Wqkvb);
    k_pack_bias<<<12, 256, 0, stream>>>(bq, bk, bv, bqkv);

    gemm_bt<0><<<dim3(24, 64), 256, 0, stream>>>(Xb, Wqkvb, 8192, 3072, 1024,
                                                 bqkv, nullptr, nullptr, Qb, Kb, Vtb);

    attn_fwd<<<dim3(32, 64), 256, 0, stream>>>(Qb, Kb, Vtb, Ctxb);

    gemm_bt<1><<<dim3(8, 64), 256, 0, stream>>>(Ctxb, Woutb, 8192, 1024, 1024,
                                                bout, drop, out, nullptr, nullptr, nullptr);
}

// Round 3
// 307.340 us; speedup vs baseline: 2.0163x; 2.0163x over previous
//
#include <hip/hip_runtime.h>
#include <stdint.h>
#include <stddef.h>

typedef short s8v __attribute__((ext_vector_type(8)));   // 8 bf16 (bit pattern in shorts)
typedef float f4  __attribute__((ext_vector_type(4)));
typedef unsigned int u32;

#define SCALE2_ 0.18033688011112042f   /* 0.125 * log2(e) — softmax in exp2 domain */
#define NEG_BIG -3.0e38f

static __device__ __forceinline__ short f2bf(float f) {
    u32 u = __builtin_bit_cast(u32, f);
    u = (u + 0x7fffu + ((u >> 16) & 1u)) >> 16;
    return (short)u;
}

// ---------------- pack / convert kernels ----------------

__global__ __launch_bounds__(256) void k_cvt(const float* __restrict__ in,
                                             s8v* __restrict__ out, int n8) {
    int i = blockIdx.x * 256 + threadIdx.x;
    if (i >= n8) return;
    const float4* p = (const float4*)in;
    float4 a = p[2 * i], b = p[2 * i + 1];
    s8v o;
    o[0] = f2bf(a.x); o[1] = f2bf(a.y); o[2] = f2bf(a.z); o[3] = f2bf(a.w);
    o[4] = f2bf(b.x); o[5] = f2bf(b.y); o[6] = f2bf(b.z); o[7] = f2bf(b.w);
    out[i] = o;
}

// Wq/Wk/Wv: (16,1024,64) each -> Wqkv_bt[n][d], n = p*1024 + h*64 + k  (B^T form, N x K)
__global__ __launch_bounds__(256) void k_pack_wqkv(const float* __restrict__ Wq,
                                                   const float* __restrict__ Wk,
                                                   const float* __restrict__ Wv,
                                                   s8v* __restrict__ out) {
    int idx = blockIdx.x * 256 + threadIdx.x;   // 3072*128 threads
    int n = idx >> 7, d8 = idx & 127;
    const float* W = (n < 1024) ? Wq : ((n < 2048) ? Wk : Wv);
    int nn = n & 1023;
    const float* src = W + (size_t)((nn >> 6) * 1024 + d8 * 8) * 64 + (nn & 63);
    s8v o;
    #pragma unroll
    for (int i = 0; i < 8; i++) o[i] = f2bf(src[i * 64]);
    out[idx] = o;
}

__global__ __launch_bounds__(256) void k_pack_bias(const float* __restrict__ bq,
                                                   const float* __restrict__ bk,
                                                   const float* __restrict__ bv,
                                                   float* __restrict__ o) {
    int n = blockIdx.x * 256 + threadIdx.x;
    if (n >= 3072) return;
    const float* b = (n < 1024) ? bq : ((n < 2048) ? bk : bv);
    o[n] = b[n & 1023];
}

// ---------------- GEMM: C = A(MxK) * Bt(NxK)^T, bf16 in, custom epilogue ----------------
// EPI=0: QKV projection -> scatter bf16 into Q[bh][t][k], K[bh][t][k], V^T[bh][v][t]
// EPI=1: output projection -> fp32 out = (acc + bout[n]) * drop[m][n]

template <int EPI>
__global__ __launch_bounds__(256) void gemm_bt(
    const short* __restrict__ A, const short* __restrict__ Bt,
    int M, int N, int K,
    const float* __restrict__ bias,
    const float* __restrict__ drop, float* __restrict__ outf,
    short* __restrict__ outq, short* __restrict__ outk, short* __restrict__ outv)
{
    __shared__ short lA[128 * 64];
    __shared__ short lB[128 * 64];
    const int tid = threadIdx.x;
    const int w = tid >> 6, l = tid & 63;
    const int wm = w >> 1, wn = w & 1;
    const int lr = l & 15, lg = l >> 4;
    const int bm = blockIdx.y * 128, bn = blockIdx.x * 128;

    f4 acc[4][4] = {};

    const short* Ab = A + (size_t)bm * K + (size_t)(l >> 3) * K + (l & 7) * 8;
    const short* Bb = Bt + (size_t)bn * K + (size_t)(l >> 3) * K + (l & 7) * 8;

    const int nk = K >> 6;
    for (int ks = 0; ks < nk; ks++) {
        const size_t koff = (size_t)ks * 64;
        #pragma unroll
        for (int i = 0; i < 4; i++) {
            const int rr = (i * 4 + w) * 8;
            __builtin_amdgcn_global_load_lds(
                (const __attribute__((address_space(1))) void*)(Ab + (size_t)rr * K + koff),
                (__attribute__((address_space(3))) void*)(&lA[rr * 64]), 16, 0, 0);
            __builtin_amdgcn_global_load_lds(
                (const __attribute__((address_space(1))) void*)(Bb + (size_t)rr * K + koff),
                (__attribute__((address_space(3))) void*)(&lB[rr * 64]), 16, 0, 0);
        }
        __syncthreads();
        #pragma unroll
        for (int c = 0; c < 2; c++) {
            s8v af[4], bfv[4];
            #pragma unroll
            for (int mt = 0; mt < 4; mt++)
                af[mt] = *(const s8v*)&lA[(wm * 64 + mt * 16 + lr) * 64 + c * 32 + lg * 8];
            #pragma unroll
            for (int nt = 0; nt < 4; nt++)
                bfv[nt] = *(const s8v*)&lB[(wn * 64 + nt * 16 + lr) * 64 + c * 32 + lg * 8];
            #pragma unroll
            for (int mt = 0; mt < 4; mt++)
                #pragma unroll
                for (int nt = 0; nt < 4; nt++)
                    acc[mt][nt] = __builtin_amdgcn_mfma_f32_16x16x32_bf16(
                        af[mt], bfv[nt], acc[mt][nt], 0, 0, 0);
        }
        __syncthreads();
    }

    #pragma unroll
    for (int mt = 0; mt < 4; mt++) {
        #pragma unroll
        for (int nt = 0; nt < 4; nt++) {
            const int n = bn + wn * 64 + nt * 16 + lr;
            const float bb = bias[n];
            #pragma unroll
            for (int j = 0; j < 4; j++) {
                const int m = bm + wm * 64 + mt * 16 + lg * 4 + j;
                const float v = acc[mt][nt][j] + bb;
                if (EPI == 0) {
                    const int p = n >> 10, hh = (n >> 6) & 15, kk = n & 63;
                    const int b = m >> 11, t = m & 2047;
                    const size_t bh = (size_t)(b * 16 + hh);
                    if (p == 0)      outq[(bh * 2048 + t) * 64 + kk] = f2bf(v);
                    else if (p == 1) outk[(bh * 2048 + t) * 64 + kk] = f2bf(v);
                    else             outv[bh * 131072 + (size_t)kk * 2048 + t] = f2bf(v); // V^T
                } else {
                    const size_t off = (size_t)m * N + n;
                    outf[off] = v * drop[off];
                }
            }
        }
    }
}

// ---------------- flash attention (causal, work-balanced) ----------------
// Q,K: bf16 [bh][t][64]. Vt: bf16 [bh][v][t] (pre-transposed). Ctx: bf16 [bh][t][64].
// Block p handles q-tiles (31-p) and (p): 33 kv-iters each -> perfectly balanced.
// 4 waves/block, wave w owns q rows qt0..qt0+15 of each tile.
// V^T double-buffered in LDS via global_load_lds with XOR chunk swizzle (T2/rule21).
// Swapped QK^T: accs = K*Q^T (row=key,col=q). PV: acc_o = V^T*P^T (row=v,col=q).

__global__ __launch_bounds__(256, 4) void attn_fwd(
    const short* __restrict__ Q, const short* __restrict__ Kv,
    const short* __restrict__ Vt, short* __restrict__ Ctx)
{
    const int bh = blockIdx.y;
    const int p = blockIdx.x;                    // 0..15
    const int tid = threadIdx.x, w = tid >> 6, l = tid & 63;
    const int lr = l & 15, lg = l >> 4;

    __shared__ short VbA[64 * 64];      // V^T tile buffers, linear, XOR-swizzled content
    __shared__ short VbB[64 * 64];
    __shared__ short Pl[4][16][72];     // per-wave P: [q][key], padded

    const size_t base = (size_t)bh * 131072;
    const short* Kg = Kv + base;
    const short* Vg = Vt + base;

    // stage kv-tile j: LDS[row][c] = global[row][c ^ (row&7)] (16B chunks c)
    auto stageV = [&](int j, short* vb) {
        const short* src0 = Vg + (size_t)j * 64;
        #pragma unroll
        for (int i = 0; i < 2; i++) {
            const int row = w * 16 + i * 8 + (l >> 3);
            const int cg = (l & 7) ^ (l >> 3);
            __builtin_amdgcn_global_load_lds(
                (const __attribute__((address_space(1))) void*)(src0 + (size_t)row * 2048 + cg * 8),
                (__attribute__((address_space(3))) void*)(vb + (w * 16 + i * 8) * 64), 16, 0, 0);
        }
    };

    auto run_tile = [&](const int qb) {
        const int nj = qb + 1;
        const int qt0 = qb * 64 + w * 16;
        const int qrow = qt0 + lr;

        const s8v q0 = *(const s8v*)&Q[base + (size_t)(qt0 + lr) * 64 + lg * 8];
        const s8v q1 = *(const s8v*)&Q[base + (size_t)(qt0 + lr) * 64 + 32 + lg * 8];

        f4 acc_o[4] = {};
        float m_run = NEG_BIG, l_run = 0.f;

        s8v kf[4][2];
        stageV(0, VbA);
        #pragma unroll
        for (int kt = 0; kt < 4; kt++) {
            const short* kp = Kg + (size_t)(kt * 16 + lr) * 64 + lg * 8;
            kf[kt][0] = *(const s8v*)kp;
            kf[kt][1] = *(const s8v*)(kp + 32);
        }

        for (int j = 0; j < nj; j++) {
            __syncthreads();                       // stage(j)+K(j) drained; prev PV done
            if (j + 1 < nj) stageV(j + 1, (j & 1) ? VbA : VbB);
            const short* vb = (j & 1) ? VbB : VbA;

            // S^T = K * Q^T
            f4 accs[4] = {};
            #pragma unroll
            for (int kt = 0; kt < 4; kt++) {
                accs[kt] = __builtin_amdgcn_mfma_f32_16x16x32_bf16(kf[kt][0], q0, accs[kt], 0, 0, 0);
                accs[kt] = __builtin_amdgcn_mfma_f32_16x16x32_bf16(kf[kt][1], q1, accs[kt], 0, 0, 0);
            }
            // register-prefetch K(j+1) (slack = softmax + PV + barrier)
            if (j + 1 < nj) {
                #pragma unroll
                for (int kt = 0; kt < 4; kt++) {
                    const short* kp = Kg + (size_t)((j + 1) * 64 + kt * 16 + lr) * 64 + lg * 8;
                    kf[kt][0] = *(const s8v*)kp;
                    kf[kt][1] = *(const s8v*)(kp + 32);
                }
            }

            // scale (+ causal mask on diagonal tile only), running max
            float pm = NEG_BIG;
            if (j == nj - 1) {
                #pragma unroll
                for (int kt = 0; kt < 4; kt++)
                    #pragma unroll
                    for (int r = 0; r < 4; r++) {
                        const int key = j * 64 + kt * 16 + lg * 4 + r;
                        float vv = accs[kt][r] * SCALE2_;
                        vv = (key > qrow) ? NEG_BIG : vv;
                        accs[kt][r] = vv;
                        pm = fmaxf(pm, vv);
                    }
            } else {
                #pragma unroll
                for (int kt = 0; kt < 4; kt++)
                    #pragma unroll
                    for (int r = 0; r < 4; r++) {
                        const float vv = accs[kt][r] * SCALE2_;
                        accs[kt][r] = vv;
                        pm = fmaxf(pm, vv);
                    }
            }
            pm = fmaxf(pm, __shfl_xor(pm, 16));
            pm = fmaxf(pm, __shfl_xor(pm, 32));

            // defer-max (T13, THR=8)
            if (!__all(pm <= m_run + 8.f)) {
                const float m_new = fmaxf(m_run, pm);
                const float so = exp2f(m_run - m_new);
                l_run *= so;
                #pragma unroll
                for (int vt = 0; vt < 4; vt++) {
                    acc_o[vt][0] *= so; acc_o[vt][1] *= so;
                    acc_o[vt][2] *= so; acc_o[vt][3] *= so;
                }
                m_run = m_new;
            }

            // exp2 + row-sum + pack P -> per-wave LDS [q][key]
            float ps = 0.f;
            #pragma unroll
            for (int kt = 0; kt < 4; kt++) {
                const float e0 = exp2f(accs[kt][0] - m_run);
                const float e1 = exp2f(accs[kt][1] - m_run);
                const float e2 = exp2f(accs[kt][2] - m_run);
                const float e3 = exp2f(accs[kt][3] - m_run);
                ps += (e0 + e1) + (e2 + e3);
                short4 pk;
                pk.x = f2bf(e0); pk.y = f2bf(e1); pk.z = f2bf(e2); pk.w = f2bf(e3);
                *(short4*)&Pl[w][lr][kt * 16 + lg * 4] = pk;
            }
            ps += __shfl_xor(ps, 16);
            ps += __shfl_xor(ps, 32);
            l_run += ps;

            // O^T += V^T * P^T  (V from LDS, XOR-swizzled read; P wave-synchronous)
            #pragma unroll
            for (int c = 0; c < 2; c++) {
                const s8v pf = *(const s8v*)&Pl[w][lr][c * 32 + lg * 8];
                #pragma unroll
                for (int vt = 0; vt < 4; vt++) {
                    const s8v vfr = *(const s8v*)&vb[(vt * 16 + lr) * 64
                                                     + (((c * 4 + lg) ^ (lr & 7)) << 3)];
                    acc_o[vt] = __builtin_amdgcn_mfma_f32_16x16x32_bf16(
                        vfr, pf, acc_o[vt], 0, 0, 0);
                }
            }
        }

        // epilogue: normalize, transpose via per-wave LDS, coalesced bf16 store
        const float inv = 1.f / l_run;
        #pragma unroll
        for (int vt = 0; vt < 4; vt++) {
            short4 ob;
            ob.x = f2bf(acc_o[vt][0] * inv);
            ob.y = f2bf(acc_o[vt][1] * inv);
            ob.z = f2bf(acc_o[vt][2] * inv);
            ob.w = f2bf(acc_o[vt][3] * inv);
            *(short4*)&Pl[w][lr][vt * 16 + lg * 4] = ob;
        }
        {
            const int qq = l >> 2;
            const int c0 = (l & 3) * 16;
            const s8v o0 = *(const s8v*)&Pl[w][qq][c0];
            const s8v o1 = *(const s8v*)&Pl[w][qq][c0 + 8];
            short* dst = (short*)&Ctx[base + (size_t)(qt0 + qq) * 64 + c0];
            *(s8v*)dst = o0;
            *(s8v*)(dst + 8) = o1;
        }
    };

    run_tile(31 - p);
    __syncthreads();        // protect LDS buffers across tiles
    run_tile(p);
}

// ---------------- launch ----------------

#define WS_XB   ((size_t)0)
#define WS_WQKV ((size_t)16777216)
#define WS_WOUT ((size_t)23068672)
#define WS_BQKV ((size_t)25165824)
#define WS_Q    ((size_t)25178112)
#define WS_K    ((size_t)41955328)
#define WS_V    ((size_t)58732544)
#define WS_CTX  ((size_t)75509760)

extern "C" void kernel_launch(void* const* d_in, const int* in_sizes, int n_in,
                              void* d_out, int out_size, void* d_ws, size_t ws_size,
                              hipStream_t stream) {
    const float* x    = (const float*)d_in[0];
    // d_in[1] = attn_mask (causal, hardcoded in attn_fwd)
    const float* Wq   = (const float*)d_in[2];
    const float* bq   = (const float*)d_in[3];
    const float* Wk   = (const float*)d_in[4];
    const float* bk   = (const float*)d_in[5];
    const float* Wv   = (const float*)d_in[6];
    const float* bv   = (const float*)d_in[7];
    const float* Wout = (const float*)d_in[8];
    const float* bout = (const float*)d_in[9];
    const float* drop = (const float*)d_in[10];
    float* out = (float*)d_out;

    char* ws = (char*)d_ws;
    short* Xb    = (short*)(ws + WS_XB);
    short* Wqkvb = (short*)(ws + WS_WQKV);
    short* Woutb = (short*)(ws + WS_WOUT);
    float* bqkv  = (float*)(ws + WS_BQKV);
    short* Qb    = (short*)(ws + WS_Q);
    short* Kb    = (short*)(ws + WS_K);
    short* Vtb   = (short*)(ws + WS_V);     // V stored TRANSPOSED: [bh][v][t]
    short* Ctxb  = (short*)(ws + WS_CTX);

    k_cvt<<<4096, 256, 0, stream>>>(x, (s8v*)Xb, 1048576);          // x -> bf16
    k_cvt<<<512, 256, 0, stream>>>(Wout, (s8v*)Woutb, 131072);      // Wout -> bf16 (already B^T form)
    k_pack_wqkv<<<1536, 256, 0, stream>>>(Wq, Wk, Wv, (s8v*)Wqkvb);
    k_pack_bias<<<12, 256, 0, stream>>>(bq, bk, bv, bqkv);

    gemm_bt<0><<<dim3(24, 64), 256, 0, stream>>>(Xb, Wqkvb, 8192, 3072, 1024,
                                                 bqkv, nullptr, nullptr, Qb, Kb, Vtb);

    attn_fwd<<<dim3(16, 64), 256, 0, stream>>>(Qb, Kb, Vtb, Ctxb);

    gemm_bt<1><<<dim3(8, 64), 256, 0, stream>>>(Ctxb, Woutb, 8192, 1024, 1024,
                                                bout, drop, out, nullptr, nullptr, nullptr);
}

// Round 4
// 279.049 us; speedup vs baseline: 2.2207x; 1.1014x over previous
//
#include <hip/hip_runtime.h>
#include <stdint.h>
#include <stddef.h>

typedef short s8v __attribute__((ext_vector_type(8)));   // 8 bf16 (bit pattern in shorts)
typedef float f4  __attribute__((ext_vector_type(4)));
typedef unsigned int u32;
typedef unsigned int u32x2 __attribute__((ext_vector_type(2)));

#define SCALE2_ 0.18033688011112042f   /* 0.125 * log2(e) — folded into Q projection */
#define NEG_BIG -3.0e38f

static __device__ __forceinline__ short f2bf(float f) {
    u32 u = __builtin_bit_cast(u32, f);
    u = (u + 0x7fffu + ((u >> 16) & 1u)) >> 16;
    return (short)u;
}

// packed f32x2 -> bf16x2 (RNE), single HW instr (T12 primitive)
static __device__ __forceinline__ u32 cvtpk(float lo, float hi) {
    u32 r;
    asm("v_cvt_pk_bf16_f32 %0, %1, %2" : "=v"(r) : "v"(lo), "v"(hi));
    return r;
}

// ---------------- pack / convert kernels ----------------

__global__ __launch_bounds__(256) void k_cvt(const float* __restrict__ in,
                                             s8v* __restrict__ out, int n8) {
    int i = blockIdx.x * 256 + threadIdx.x;
    if (i >= n8) return;
    const float4* p = (const float4*)in;
    float4 a = p[2 * i], b = p[2 * i + 1];
    s8v o;
    o[0] = f2bf(a.x); o[1] = f2bf(a.y); o[2] = f2bf(a.z); o[3] = f2bf(a.w);
    o[4] = f2bf(b.x); o[5] = f2bf(b.y); o[6] = f2bf(b.z); o[7] = f2bf(b.w);
    out[i] = o;
}

// Wq/Wk/Wv: (16,1024,64) each -> Wqkv_bt[n][d], n = p*1024 + h*64 + k  (B^T form, N x K)
// Q weights pre-scaled by SCALE2_ (softmax scale folded into projection).
__global__ __launch_bounds__(256) void k_pack_wqkv(const float* __restrict__ Wq,
                                                   const float* __restrict__ Wk,
                                                   const float* __restrict__ Wv,
                                                   s8v* __restrict__ out) {
    int idx = blockIdx.x * 256 + threadIdx.x;   // 3072*128 threads
    int n = idx >> 7, d8 = idx & 127;
    const float* W = (n < 1024) ? Wq : ((n < 2048) ? Wk : Wv);
    const float sc = (n < 1024) ? SCALE2_ : 1.0f;
    int nn = n & 1023;
    const float* src = W + (size_t)((nn >> 6) * 1024 + d8 * 8) * 64 + (nn & 63);
    s8v o;
    #pragma unroll
    for (int i = 0; i < 8; i++) o[i] = f2bf(src[i * 64] * sc);
    out[idx] = o;
}

__global__ __launch_bounds__(256) void k_pack_bias(const float* __restrict__ bq,
                                                   const float* __restrict__ bk,
                                                   const float* __restrict__ bv,
                                                   float* __restrict__ o) {
    int n = blockIdx.x * 256 + threadIdx.x;
    if (n >= 3072) return;
    const float* b = (n < 1024) ? bq : ((n < 2048) ? bk : bv);
    o[n] = b[n & 1023] * ((n < 1024) ? SCALE2_ : 1.0f);
}

// ---------------- GEMM: C = A(MxK) * Bt(NxK)^T, bf16 in, custom epilogue ----------------
// EPI=0: QKV projection -> scatter bf16 into Q[bh][t][k], K[bh][t][k], V^T[bh][v][t]
// EPI=1: output projection -> fp32 out = (acc + bout[n]) * drop[m][n]

template <int EPI>
__global__ __launch_bounds__(256) void gemm_bt(
    const short* __restrict__ A, const short* __restrict__ Bt,
    int M, int N, int K,
    const float* __restrict__ bias,
    const float* __restrict__ drop, float* __restrict__ outf,
    short* __restrict__ outq, short* __restrict__ outk, short* __restrict__ outv)
{
    __shared__ short lA[128 * 64];
    __shared__ short lB[128 * 64];
    const int tid = threadIdx.x;
    const int w = tid >> 6, l = tid & 63;
    const int wm = w >> 1, wn = w & 1;
    const int lr = l & 15, lg = l >> 4;
    const int bm = blockIdx.y * 128, bn = blockIdx.x * 128;

    f4 acc[4][4] = {};

    const short* Ab = A + (size_t)bm * K + (size_t)(l >> 3) * K + (l & 7) * 8;
    const short* Bb = Bt + (size_t)bn * K + (size_t)(l >> 3) * K + (l & 7) * 8;

    const int nk = K >> 6;
    for (int ks = 0; ks < nk; ks++) {
        const size_t koff = (size_t)ks * 64;
        #pragma unroll
        for (int i = 0; i < 4; i++) {
            const int rr = (i * 4 + w) * 8;
            __builtin_amdgcn_global_load_lds(
                (const __attribute__((address_space(1))) void*)(Ab + (size_t)rr * K + koff),
                (__attribute__((address_space(3))) void*)(&lA[rr * 64]), 16, 0, 0);
            __builtin_amdgcn_global_load_lds(
                (const __attribute__((address_space(1))) void*)(Bb + (size_t)rr * K + koff),
                (__attribute__((address_space(3))) void*)(&lB[rr * 64]), 16, 0, 0);
        }
        __syncthreads();
        #pragma unroll
        for (int c = 0; c < 2; c++) {
            s8v af[4], bfv[4];
            #pragma unroll
            for (int mt = 0; mt < 4; mt++)
                af[mt] = *(const s8v*)&lA[(wm * 64 + mt * 16 + lr) * 64 + c * 32 + lg * 8];
            #pragma unroll
            for (int nt = 0; nt < 4; nt++)
                bfv[nt] = *(const s8v*)&lB[(wn * 64 + nt * 16 + lr) * 64 + c * 32 + lg * 8];
            #pragma unroll
            for (int mt = 0; mt < 4; mt++)
                #pragma unroll
                for (int nt = 0; nt < 4; nt++)
                    acc[mt][nt] = __builtin_amdgcn_mfma_f32_16x16x32_bf16(
                        af[mt], bfv[nt], acc[mt][nt], 0, 0, 0);
        }
        __syncthreads();
    }

    const int pblk = bn >> 10;   // block-uniform: which of Q/K/V this tile feeds (EPI=0)
    #pragma unroll
    for (int mt = 0; mt < 4; mt++) {
        #pragma unroll
        for (int nt = 0; nt < 4; nt++) {
            const int n = bn + wn * 64 + nt * 16 + lr;
            const float bb = bias[n];
            const int m0 = bm + wm * 64 + mt * 16 + lg * 4;
            if (EPI == 0) {
                const int hh = (n >> 6) & 15, kk = n & 63;
                const int b = m0 >> 11, t0 = m0 & 2047;
                const size_t bh = (size_t)(b * 16 + hh);
                if (pblk == 2) {      // V^T: consecutive t -> one 8B store
                    const u32 r0 = cvtpk(acc[mt][nt][0] + bb, acc[mt][nt][1] + bb);
                    const u32 r1 = cvtpk(acc[mt][nt][2] + bb, acc[mt][nt][3] + bb);
                    u32x2 pr = {r0, r1};
                    *(u32x2*)&outv[bh * 131072 + (size_t)kk * 2048 + t0] = pr;
                } else {
                    short* dst = (pblk == 0) ? outq : outk;
                    #pragma unroll
                    for (int j = 0; j < 4; j++)
                        dst[(bh * 2048 + (t0 + j)) * 64 + kk] = f2bf(acc[mt][nt][j] + bb);
                }
            } else {
                #pragma unroll
                for (int j = 0; j < 4; j++) {
                    const size_t off = (size_t)(m0 + j) * N + n;
                    outf[off] = (acc[mt][nt][j] + bb) * drop[off];
                }
            }
        }
    }
}

// ---------------- flash attention (causal, work-balanced, XCD-local) ----------------
// Q (pre-scaled),K: bf16 [bh][t][64]. Vt: bf16 [bh][v][t]. Ctx: bf16 [bh][t][64].
// Block handles q-tiles (31-p) and (p): 33 kv-iters each -> perfectly balanced.
// XCD mapping: i&7 = XCD slot; 8 consecutive bh per XCD -> K/V L2-resident (T1).
// V^T double-buffered in LDS via global_load_lds + XOR chunk swizzle (T2/rule21).
// Swapped QK^T: accs = K*Q^T (row=key,col=q). PV: acc_o = V^T*P^T (row=v,col=q).

__global__ __launch_bounds__(256, 4) void attn_fwd(
    const short* __restrict__ Q, const short* __restrict__ Kv,
    const short* __restrict__ Vt, short* __restrict__ Ctx)
{
    const int i = blockIdx.x;                    // 0..1023
    const int bh = (i & 7) * 8 + ((i >> 3) & 7);
    const int p = i >> 6;                        // 0..15
    const int tid = threadIdx.x, w = tid >> 6, l = tid & 63;
    const int lr = l & 15, lg = l >> 4;

    __shared__ short VbA[64 * 64];      // V^T tile buffers, linear, XOR-swizzled content
    __shared__ short VbB[64 * 64];
    __shared__ short Pl[4][16][72];     // per-wave P: [q][key], padded

    const size_t base = (size_t)bh * 131072;
    const short* Kg = Kv + base;
    const short* Vg = Vt + base;

    // stage kv-tile j: LDS[row][c] = global[row][c ^ (row&7)] (16B chunks c)
    auto stageV = [&](int j, short* vb) {
        const short* src0 = Vg + (size_t)j * 64;
        #pragma unroll
        for (int i2 = 0; i2 < 2; i2++) {
            const int row = w * 16 + i2 * 8 + (l >> 3);
            const int cg = (l & 7) ^ (l >> 3);
            __builtin_amdgcn_global_load_lds(
                (const __attribute__((address_space(1))) void*)(src0 + (size_t)row * 2048 + cg * 8),
                (__attribute__((address_space(3))) void*)(vb + (w * 16 + i2 * 8) * 64), 16, 0, 0);
        }
    };

    auto run_tile = [&](const int qb) {
        const int nj = qb + 1;
        const int qt0 = qb * 64 + w * 16;
        const int qrow = qt0 + lr;

        const s8v q0 = *(const s8v*)&Q[base + (size_t)(qt0 + lr) * 64 + lg * 8];
        const s8v q1 = *(const s8v*)&Q[base + (size_t)(qt0 + lr) * 64 + 32 + lg * 8];

        f4 acc_o[4] = {};
        float m_run = NEG_BIG, l_run = 0.f;

        s8v kf[4][2];
        stageV(0, VbA);
        #pragma unroll
        for (int kt = 0; kt < 4; kt++) {
            const short* kp = Kg + (size_t)(kt * 16 + lr) * 64 + lg * 8;
            kf[kt][0] = *(const s8v*)kp;
            kf[kt][1] = *(const s8v*)(kp + 32);
        }

        for (int j = 0; j < nj; j++) {
            __syncthreads();                       // stage(j)+K(j) drained; prev PV done
            if (j + 1 < nj) stageV(j + 1, (j & 1) ? VbA : VbB);
            const short* vb = (j & 1) ? VbB : VbA;

            // S^T = K * Q^T  (Q pre-scaled -> result already in exp2 domain)
            f4 accs[4] = {};
            #pragma unroll
            for (int kt = 0; kt < 4; kt++) {
                accs[kt] = __builtin_amdgcn_mfma_f32_16x16x32_bf16(kf[kt][0], q0, accs[kt], 0, 0, 0);
                accs[kt] = __builtin_amdgcn_mfma_f32_16x16x32_bf16(kf[kt][1], q1, accs[kt], 0, 0, 0);
            }
            // register-prefetch K(j+1) (slack = softmax + PV + barrier)
            if (j + 1 < nj) {
                #pragma unroll
                for (int kt = 0; kt < 4; kt++) {
                    const short* kp = Kg + (size_t)((j + 1) * 64 + kt * 16 + lr) * 64 + lg * 8;
                    kf[kt][0] = *(const s8v*)kp;
                    kf[kt][1] = *(const s8v*)(kp + 32);
                }
            }

            // causal mask on diagonal tile only
            if (j == nj - 1) {
                #pragma unroll
                for (int kt = 0; kt < 4; kt++)
                    #pragma unroll
                    for (int r = 0; r < 4; r++) {
                        const int key = j * 64 + kt * 16 + lg * 4 + r;
                        if (key > qrow) accs[kt][r] = NEG_BIG;
                    }
            }

            // tile max (tree, depth 4) + cross-lane
            float mxk[4];
            #pragma unroll
            for (int kt = 0; kt < 4; kt++)
                mxk[kt] = fmaxf(fmaxf(accs[kt][0], accs[kt][1]),
                                fmaxf(accs[kt][2], accs[kt][3]));
            float pm = fmaxf(fmaxf(mxk[0], mxk[1]), fmaxf(mxk[2], mxk[3]));
            pm = fmaxf(pm, __shfl_xor(pm, 16));
            pm = fmaxf(pm, __shfl_xor(pm, 32));

            // defer-max (T13, THR=8)
            if (!__all(pm <= m_run + 8.f)) {
                const float m_new = fmaxf(m_run, pm);
                const float so = exp2f(m_run - m_new);
                l_run *= so;
                #pragma unroll
                for (int vt = 0; vt < 4; vt++) {
                    acc_o[vt][0] *= so; acc_o[vt][1] *= so;
                    acc_o[vt][2] *= so; acc_o[vt][3] *= so;
                }
                m_run = m_new;
            }

            // exp2 + row-sum (tree) + cvt_pk pack -> per-wave LDS [q][key]
            float sk[4];
            #pragma unroll
            for (int kt = 0; kt < 4; kt++) {
                const float e0 = exp2f(accs[kt][0] - m_run);
                const float e1 = exp2f(accs[kt][1] - m_run);
                const float e2 = exp2f(accs[kt][2] - m_run);
                const float e3 = exp2f(accs[kt][3] - m_run);
                sk[kt] = (e0 + e1) + (e2 + e3);
                const u32 r0 = cvtpk(e0, e1);
                const u32 r1 = cvtpk(e2, e3);
                u32x2 pr = {r0, r1};
                *(u32x2*)&Pl[w][lr][kt * 16 + lg * 4] = pr;
            }
            float ps = (sk[0] + sk[1]) + (sk[2] + sk[3]);
            ps += __shfl_xor(ps, 16);
            ps += __shfl_xor(ps, 32);
            l_run += ps;

            // O^T += V^T * P^T  (V from LDS, XOR-swizzled read; P wave-synchronous)
            #pragma unroll
            for (int c = 0; c < 2; c++) {
                const s8v pf = *(const s8v*)&Pl[w][lr][c * 32 + lg * 8];
                #pragma unroll
                for (int vt = 0; vt < 4; vt++) {
                    const s8v vfr = *(const s8v*)&vb[(vt * 16 + lr) * 64
                                                     + (((c * 4 + lg) ^ (lr & 7)) << 3)];
                    acc_o[vt] = __builtin_amdgcn_mfma_f32_16x16x32_bf16(
                        vfr, pf, acc_o[vt], 0, 0, 0);
                }
            }
        }

        // epilogue: normalize, transpose via per-wave LDS, coalesced bf16 store
        const float inv = 1.f / l_run;
        #pragma unroll
        for (int vt = 0; vt < 4; vt++) {
            const u32 r0 = cvtpk(acc_o[vt][0] * inv, acc_o[vt][1] * inv);
            const u32 r1 = cvtpk(acc_o[vt][2] * inv, acc_o[vt][3] * inv);
            u32x2 pr = {r0, r1};
            *(u32x2*)&Pl[w][lr][vt * 16 + lg * 4] = pr;
        }
        {
            const int qq = l >> 2;
            const int c0 = (l & 3) * 16;
            const s8v o0 = *(const s8v*)&Pl[w][qq][c0];
            const s8v o1 = *(const s8v*)&Pl[w][qq][c0 + 8];
            short* dst = (short*)&Ctx[base + (size_t)(qt0 + qq) * 64 + c0];
            *(s8v*)dst = o0;
            *(s8v*)(dst + 8) = o1;
        }
    };

    run_tile(31 - p);
    __syncthreads();        // protect LDS buffers across tiles
    run_tile(p);
}

// ---------------- launch ----------------

#define WS_XB   ((size_t)0)
#define WS_WQKV ((size_t)16777216)
#define WS_WOUT ((size_t)23068672)
#define WS_BQKV ((size_t)25165824)
#define WS_Q    ((size_t)25178112)
#define WS_K    ((size_t)41955328)
#define WS_V    ((size_t)58732544)
#define WS_CTX  ((size_t)75509760)

extern "C" void kernel_launch(void* const* d_in, const int* in_sizes, int n_in,
                              void* d_out, int out_size, void* d_ws, size_t ws_size,
                              hipStream_t stream) {
    const float* x    = (const float*)d_in[0];
    // d_in[1] = attn_mask (causal, hardcoded in attn_fwd)
    const float* Wq   = (const float*)d_in[2];
    const float* bq   = (const float*)d_in[3];
    const float* Wk   = (const float*)d_in[4];
    const float* bk   = (const float*)d_in[5];
    const float* Wv   = (const float*)d_in[6];
    const float* bv   = (const float*)d_in[7];
    const float* Wout = (const float*)d_in[8];
    const float* bout = (const float*)d_in[9];
    const float* drop = (const float*)d_in[10];
    float* out = (float*)d_out;

    char* ws = (char*)d_ws;
    short* Xb    = (short*)(ws + WS_XB);
    short* Wqkvb = (short*)(ws + WS_WQKV);
    short* Woutb = (short*)(ws + WS_WOUT);
    float* bqkv  = (float*)(ws + WS_BQKV);
    short* Qb    = (short*)(ws + WS_Q);
    short* Kb    = (short*)(ws + WS_K);
    short* Vtb   = (short*)(ws + WS_V);     // V stored TRANSPOSED: [bh][v][t]
    short* Ctxb  = (short*)(ws + WS_CTX);

    k_cvt<<<4096, 256, 0, stream>>>(x, (s8v*)Xb, 1048576);          // x -> bf16
    k_cvt<<<512, 256, 0, stream>>>(Wout, (s8v*)Woutb, 131072);      // Wout -> bf16 (already B^T form)
    k_pack_wqkv<<<1536, 256, 0, stream>>>(Wq, Wk, Wv, (s8v*)Wqkvb);
    k_pack_bias<<<12, 256, 0, stream>>>(bq, bk, bv, bqkv);

    gemm_bt<0><<<dim3(24, 64), 256, 0, stream>>>(Xb, Wqkvb, 8192, 3072, 1024,
                                                 bqkv, nullptr, nullptr, Qb, Kb, Vtb);

    attn_fwd<<<dim3(1024), 256, 0, stream>>>(Qb, Kb, Vtb, Ctxb);

    gemm_bt<1><<<dim3(8, 64), 256, 0, stream>>>(Ctxb, Woutb, 8192, 1024, 1024,
                                                bout, drop, out, nullptr, nullptr, nullptr);
}

// Round 5
// 218.683 us; speedup vs baseline: 2.8337x; 1.2760x over previous
//
#include <hip/hip_runtime.h>
#include <stdint.h>
#include <stddef.h>

typedef short s8v __attribute__((ext_vector_type(8)));   // 8 bf16 (bit pattern in shorts)
typedef float f4  __attribute__((ext_vector_type(4)));
typedef float f16v __attribute__((ext_vector_type(16)));
typedef unsigned int u32;
typedef unsigned int u32x2 __attribute__((ext_vector_type(2)));
typedef unsigned int u32x4 __attribute__((ext_vector_type(4)));

#define SCALE2_ 0.18033688011112042f   /* 0.125 * log2(e) — folded into Q projection */
#define NEG_BIG -3.0e38f
#define AS1 __attribute__((address_space(1)))
#define AS3 __attribute__((address_space(3)))

static __device__ __forceinline__ short f2bf(float f) {
    u32 u = __builtin_bit_cast(u32, f);
    u = (u + 0x7fffu + ((u >> 16) & 1u)) >> 16;
    return (short)u;
}

// packed f32x2 -> bf16x2 (RNE), single HW instr (T12 primitive)
static __device__ __forceinline__ u32 cvtpk(float lo, float hi) {
    u32 r;
    asm("v_cvt_pk_bf16_f32 %0, %1, %2" : "=v"(r) : "v"(lo), "v"(hi));
    return r;
}

// ---------------- pack / convert kernels ----------------

__global__ __launch_bounds__(256) void k_cvt(const float* __restrict__ in,
                                             s8v* __restrict__ out, int n8) {
    int i = blockIdx.x * 256 + threadIdx.x;
    if (i >= n8) return;
    const float4* p = (const float4*)in;
    float4 a = p[2 * i], b = p[2 * i + 1];
    s8v o;
    o[0] = f2bf(a.x); o[1] = f2bf(a.y); o[2] = f2bf(a.z); o[3] = f2bf(a.w);
    o[4] = f2bf(b.x); o[5] = f2bf(b.y); o[6] = f2bf(b.z); o[7] = f2bf(b.w);
    out[i] = o;
}

// Wq/Wk/Wv: (16,1024,64) each -> Wqkv_bt[n][d], n = p*1024 + h*64 + k  (B^T form, N x K)
// Q weights pre-scaled by SCALE2_ (softmax scale folded into projection).
__global__ __launch_bounds__(256) void k_pack_wqkv(const float* __restrict__ Wq,
                                                   const float* __restrict__ Wk,
                                                   const float* __restrict__ Wv,
                                                   s8v* __restrict__ out) {
    int idx = blockIdx.x * 256 + threadIdx.x;   // 3072*128 threads
    int n = idx >> 7, d8 = idx & 127;
    const float* W = (n < 1024) ? Wq : ((n < 2048) ? Wk : Wv);
    const float sc = (n < 1024) ? SCALE2_ : 1.0f;
    int nn = n & 1023;
    const float* src = W + (size_t)((nn >> 6) * 1024 + d8 * 8) * 64 + (nn & 63);
    s8v o;
    #pragma unroll
    for (int i = 0; i < 8; i++) o[i] = f2bf(src[i * 64] * sc);
    out[idx] = o;
}

__global__ __launch_bounds__(256) void k_pack_bias(const float* __restrict__ bq,
                                                   const float* __restrict__ bk,
                                                   const float* __restrict__ bv,
                                                   float* __restrict__ o) {
    int n = blockIdx.x * 256 + threadIdx.x;
    if (n >= 3072) return;
    const float* b = (n < 1024) ? bq : ((n < 2048) ? bk : bv);
    o[n] = b[n & 1023] * ((n < 1024) ? SCALE2_ : 1.0f);
}

// ---------------- GEMM: C = A(MxK) * Bt(NxK)^T, bf16 in, custom epilogue ----------------

template <int EPI>
__global__ __launch_bounds__(256) void gemm_bt(
    const short* __restrict__ A, const short* __restrict__ Bt,
    int M, int N, int K,
    const float* __restrict__ bias,
    const float* __restrict__ drop, float* __restrict__ outf,
    short* __restrict__ outq, short* __restrict__ outk, short* __restrict__ outv)
{
    __shared__ short lA[128 * 64];
    __shared__ short lB[128 * 64];
    const int tid = threadIdx.x;
    const int w = tid >> 6, l = tid & 63;
    const int wm = w >> 1, wn = w & 1;
    const int lr = l & 15, lg = l >> 4;
    const int bm = blockIdx.y * 128, bn = blockIdx.x * 128;

    f4 acc[4][4] = {};

    const short* Ab = A + (size_t)bm * K + (size_t)(l >> 3) * K + (l & 7) * 8;
    const short* Bb = Bt + (size_t)bn * K + (size_t)(l >> 3) * K + (l & 7) * 8;

    const int nk = K >> 6;
    for (int ks = 0; ks < nk; ks++) {
        const size_t koff = (size_t)ks * 64;
        #pragma unroll
        for (int i = 0; i < 4; i++) {
            const int rr = (i * 4 + w) * 8;
            __builtin_amdgcn_global_load_lds(
                (const AS1 void*)(Ab + (size_t)rr * K + koff),
                (AS3 void*)(&lA[rr * 64]), 16, 0, 0);
            __builtin_amdgcn_global_load_lds(
                (const AS1 void*)(Bb + (size_t)rr * K + koff),
                (AS3 void*)(&lB[rr * 64]), 16, 0, 0);
        }
        __syncthreads();
        #pragma unroll
        for (int c = 0; c < 2; c++) {
            s8v af[4], bfv[4];
            #pragma unroll
            for (int mt = 0; mt < 4; mt++)
                af[mt] = *(const s8v*)&lA[(wm * 64 + mt * 16 + lr) * 64 + c * 32 + lg * 8];
            #pragma unroll
            for (int nt = 0; nt < 4; nt++)
                bfv[nt] = *(const s8v*)&lB[(wn * 64 + nt * 16 + lr) * 64 + c * 32 + lg * 8];
            #pragma unroll
            for (int mt = 0; mt < 4; mt++)
                #pragma unroll
                for (int nt = 0; nt < 4; nt++)
                    acc[mt][nt] = __builtin_amdgcn_mfma_f32_16x16x32_bf16(
                        af[mt], bfv[nt], acc[mt][nt], 0, 0, 0);
        }
        __syncthreads();
    }

    const int pblk = bn >> 10;
    #pragma unroll
    for (int mt = 0; mt < 4; mt++) {
        #pragma unroll
        for (int nt = 0; nt < 4; nt++) {
            const int n = bn + wn * 64 + nt * 16 + lr;
            const float bb = bias[n];
            const int m0 = bm + wm * 64 + mt * 16 + lg * 4;
            if (EPI == 0) {
                const int hh = (n >> 6) & 15, kk = n & 63;
                const int b = m0 >> 11, t0 = m0 & 2047;
                const size_t bh = (size_t)(b * 16 + hh);
                if (pblk == 2) {      // V^T: consecutive t -> one 8B store
                    const u32 r0 = cvtpk(acc[mt][nt][0] + bb, acc[mt][nt][1] + bb);
                    const u32 r1 = cvtpk(acc[mt][nt][2] + bb, acc[mt][nt][3] + bb);
                    u32x2 pr = {r0, r1};
                    *(u32x2*)&outv[bh * 131072 + (size_t)kk * 2048 + t0] = pr;
                } else {
                    short* dst = (pblk == 0) ? outq : outk;
                    #pragma unroll
                    for (int j = 0; j < 4; j++)
                        dst[(bh * 2048 + (t0 + j)) * 64 + kk] = f2bf(acc[mt][nt][j] + bb);
                }
            } else {
                #pragma unroll
                for (int j = 0; j < 4; j++) {
                    const size_t off = (size_t)(m0 + j) * N + n;
                    outf[off] = (acc[mt][nt][j] + bb) * drop[off];
                }
            }
        }
    }
}

// ---------------- flash attention (causal, 32x32 MFMA, in-register softmax) --------------
// Q (pre-scaled),K: bf16 [bh][t][64]. Vt: bf16 [bh][v][t]. Ctx: bf16 [bh][t][64].
// Block = 4 waves x 32 q-rows = 128 q-rows. Pairing (15-p, p) -> 34 kv-iters, balanced.
// K and V^T tiles (64x64) double-buffered in LDS via global_load_lds + XOR chunk swizzle.
// Swapped QK^T (mfma_32x32x16: S^T[key][q], col=lane&31=q) -> lane owns a full half-row;
// softmax in-register; P->B-fragment via 16 cvt_pk + 8 permlane32_swap (T12).

__global__ __launch_bounds__(256, 2) void attn_fwd(
    const short* __restrict__ Q, const short* __restrict__ Kv,
    const short* __restrict__ Vt, short* __restrict__ Ctx)
{
    const int i = blockIdx.x;                    // 0..511
    const int bh = (i & 7) * 8 + ((i >> 3) & 7); // 8 blocks of a bh on one XCD (T1)
    const int p = i >> 6;                        // 0..7
    const int tid = threadIdx.x, w = tid >> 6, l = tid & 63;
    const int lq = l & 31, hh = l >> 5;

    __shared__ short KbA[64 * 64], KbB[64 * 64];   // 8 KB each
    __shared__ short VbA[64 * 64], VbB[64 * 64];
    __shared__ short Ol[4][32][72];                // per-wave O transpose buffer

    const size_t base = (size_t)bh * 131072;
    const short* Kg = Kv + base;
    const short* Vg = Vt + base;

    // stage kv-tile j: LDS[row][c] = global[row][c ^ (row&7)]  (16B chunks, rule #21)
    auto stage = [&](int j, short* kb, short* vb) {
        const int cg = (l & 7) ^ (l >> 3);
        #pragma unroll
        for (int i2 = 0; i2 < 2; i2++) {
            const int r2 = w * 16 + i2 * 8 + (l >> 3);
            __builtin_amdgcn_global_load_lds(
                (const AS1 void*)(Kg + (size_t)(j * 64 + r2) * 64 + cg * 8),
                (AS3 void*)(kb + (w * 16 + i2 * 8) * 64), 16, 0, 0);
            __builtin_amdgcn_global_load_lds(
                (const AS1 void*)(Vg + (size_t)r2 * 2048 + j * 64 + cg * 8),
                (AS3 void*)(vb + (w * 16 + i2 * 8) * 64), 16, 0, 0);
        }
    };

    auto run_tile = [&](const int qb) {
        const int nj = 2 * qb + 2;
        const int qt0 = qb * 128 + w * 32;
        const int qrow = qt0 + lq;

        s8v qf[4];
        #pragma unroll
        for (int m = 0; m < 4; m++)
            qf[m] = *(const s8v*)&Q[base + (size_t)(qt0 + lq) * 64 + m * 16 + hh * 8];

        f16v acc0 = {}, acc1 = {};            // v rows 0..31 / 32..63 (col=q)
        float m_run = NEG_BIG, l_run = 0.f;

        stage(0, KbA, VbA);

        for (int j = 0; j < nj; j++) {
            __syncthreads();                  // stage(j) drained; prev reads done
            short* kb = (j & 1) ? KbB : KbA;
            short* vb = (j & 1) ? VbB : VbA;
            if (j + 1 < nj) stage(j + 1, (j & 1) ? KbA : KbB, (j & 1) ? VbA : VbB);

            if (64 * j > qt0 + 31) continue;  // fully masked for this wave

            // S^T = K * Q^T  (two 32-key halves, K from LDS, swizzled reads)
            f16v sA = {}, sB = {};
            #pragma unroll
            for (int m = 0; m < 4; m++) {
                const int ck = ((2 * m + hh) ^ (l & 7)) * 8;
                const s8v ka = *(const s8v*)&kb[lq * 64 + ck];
                const s8v kc = *(const s8v*)&kb[(32 + lq) * 64 + ck];
                sA = __builtin_amdgcn_mfma_f32_32x32x16_bf16(ka, qf[m], sA, 0, 0, 0);
                sB = __builtin_amdgcn_mfma_f32_32x32x16_bf16(kc, qf[m], sB, 0, 0, 0);
            }

            // causal mask on boundary tiles (wave-uniform branch)
            if (64 * j + 63 > qt0) {
                #pragma unroll
                for (int r = 0; r < 16; r++) {
                    const int klo = 64 * j + (r & 3) + 8 * (r >> 2) + 4 * hh;
                    if (klo > qrow)      sA[r] = NEG_BIG;
                    if (klo + 32 > qrow) sB[r] = NEG_BIG;
                }
            }

            // in-register row max (lane's 32 values, one q) + half-row combine
            float mx[8];
            #pragma unroll
            for (int r = 0; r < 8; r++)
                mx[r] = fmaxf(fmaxf(sA[r], sA[r + 8]), fmaxf(sB[r], sB[r + 8]));
            float pm = fmaxf(fmaxf(fmaxf(mx[0], mx[1]), fmaxf(mx[2], mx[3])),
                             fmaxf(fmaxf(mx[4], mx[5]), fmaxf(mx[6], mx[7])));
            pm = fmaxf(pm, __shfl_xor(pm, 32));

            // defer-max (T13, THR=8 in exp2 domain)
            if (!__all(pm <= m_run + 8.f)) {
                const float m_new = fmaxf(m_run, pm);
                const float so = exp2f(m_run - m_new);
                l_run *= so;
                #pragma unroll
                for (int r = 0; r < 16; r++) { acc0[r] *= so; acc1[r] *= so; }
                m_run = m_new;
            }

            // exp2 in place + row sum
            #pragma unroll
            for (int r = 0; r < 16; r++) {
                sA[r] = exp2f(sA[r] - m_run);
                sB[r] = exp2f(sB[r] - m_run);
            }
            float sm[8];
            #pragma unroll
            for (int r = 0; r < 8; r++)
                sm[r] = (sA[r] + sA[r + 8]) + (sB[r] + sB[r + 8]);
            float ps = ((sm[0] + sm[1]) + (sm[2] + sm[3])) +
                       ((sm[4] + sm[5]) + (sm[6] + sm[7]));
            ps += __shfl_xor(ps, 32);
            l_run += ps;

            // P fragments (cvt_pk + permlane32_swap) + PV accumulate
            #pragma unroll
            for (int m = 0; m < 4; m++) {
                const int rb = (m & 1) * 8;
                u32 P0, P1, P2, P3;
                if (m < 2) {
                    P0 = cvtpk(sA[rb + 0], sA[rb + 1]); P1 = cvtpk(sA[rb + 2], sA[rb + 3]);
                    P2 = cvtpk(sA[rb + 4], sA[rb + 5]); P3 = cvtpk(sA[rb + 6], sA[rb + 7]);
                } else {
                    P0 = cvtpk(sB[rb + 0], sB[rb + 1]); P1 = cvtpk(sB[rb + 2], sB[rb + 3]);
                    P2 = cvtpk(sB[rb + 4], sB[rb + 5]); P3 = cvtpk(sB[rb + 6], sB[rb + 7]);
                }
                const u32x2 s02 = __builtin_amdgcn_permlane32_swap(P0, P2, false, false);
                const u32x2 s13 = __builtin_amdgcn_permlane32_swap(P1, P3, false, false);
                const u32x4 uv = {s02[0], s13[0], s02[1], s13[1]};
                const s8v pf = __builtin_bit_cast(s8v, uv);

                const int ck = ((2 * m + hh) ^ (l & 7)) * 8;
                const s8v va = *(const s8v*)&vb[lq * 64 + ck];
                const s8v vc = *(const s8v*)&vb[(32 + lq) * 64 + ck];
                acc0 = __builtin_amdgcn_mfma_f32_32x32x16_bf16(va, pf, acc0, 0, 0, 0);
                acc1 = __builtin_amdgcn_mfma_f32_32x32x16_bf16(vc, pf, acc1, 0, 0, 0);
            }
        }

        // epilogue: normalize, per-wave LDS transpose, coalesced bf16 store
        const float inv = 1.f / l_run;
        #pragma unroll
        for (int r = 0; r < 16; r += 2) {
            const int v0 = (r & 3) + 8 * (r >> 2) + 4 * hh;
            *(u32*)&Ol[w][lq][v0]      = cvtpk(acc0[r] * inv, acc0[r + 1] * inv);
            *(u32*)&Ol[w][lq][32 + v0] = cvtpk(acc1[r] * inv, acc1[r + 1] * inv);
        }
        #pragma unroll
        for (int c = 0; c < 4; c++) {
            const s8v o = *(const s8v*)&Ol[w][l >> 1][(l & 1) * 32 + c * 8];
            *(s8v*)&Ctx[base + (size_t)(qt0 + (l >> 1)) * 64 + (l & 1) * 32 + c * 8] = o;
        }
    };

    run_tile(15 - p);
    __syncthreads();        // protect LDS buffers across tiles
    run_tile(p);
}

// ---------------- launch ----------------

#define WS_XB   ((size_t)0)
#define WS_WQKV ((size_t)16777216)
#define WS_WOUT ((size_t)23068672)
#define WS_BQKV ((size_t)25165824)
#define WS_Q    ((size_t)25178112)
#define WS_K    ((size_t)41955328)
#define WS_V    ((size_t)58732544)
#define WS_CTX  ((size_t)75509760)

extern "C" void kernel_launch(void* const* d_in, const int* in_sizes, int n_in,
                              void* d_out, int out_size, void* d_ws, size_t ws_size,
                              hipStream_t stream) {
    const float* x    = (const float*)d_in[0];
    // d_in[1] = attn_mask (causal, hardcoded in attn_fwd)
    const float* Wq   = (const float*)d_in[2];
    const float* bq   = (const float*)d_in[3];
    const float* Wk   = (const float*)d_in[4];
    const float* bk   = (const float*)d_in[5];
    const float* Wv   = (const float*)d_in[6];
    const float* bv   = (const float*)d_in[7];
    const float* Wout = (const float*)d_in[8];
    const float* bout = (const float*)d_in[9];
    const float* drop = (const float*)d_in[10];
    float* out = (float*)d_out;

    char* ws = (char*)d_ws;
    short* Xb    = (short*)(ws + WS_XB);
    short* Wqkvb = (short*)(ws + WS_WQKV);
    short* Woutb = (short*)(ws + WS_WOUT);
    float* bqkv  = (float*)(ws + WS_BQKV);
    short* Qb    = (short*)(ws + WS_Q);
    short* Kb    = (short*)(ws + WS_K);
    short* Vtb   = (short*)(ws + WS_V);     // V stored TRANSPOSED: [bh][v][t]
    short* Ctxb  = (short*)(ws + WS_CTX);

    k_cvt<<<4096, 256, 0, stream>>>(x, (s8v*)Xb, 1048576);          // x -> bf16
    k_cvt<<<512, 256, 0, stream>>>(Wout, (s8v*)Woutb, 131072);      // Wout -> bf16 (B^T form)
    k_pack_wqkv<<<1536, 256, 0, stream>>>(Wq, Wk, Wv, (s8v*)Wqkvb);
    k_pack_bias<<<12, 256, 0, stream>>>(bq, bk, bv, bqkv);

    gemm_bt<0><<<dim3(24, 64), 256, 0, stream>>>(Xb, Wqkvb, 8192, 3072, 1024,
                                                 bqkv, nullptr, nullptr, Qb, Kb, Vtb);

    attn_fwd<<<dim3(512), 256, 0, stream>>>(Qb, Kb, Vtb, Ctxb);

    gemm_bt<1><<<dim3(8, 64), 256, 0, stream>>>(Ctxb, Woutb, 8192, 1024, 1024,
                                                bout, drop, out, nullptr, nullptr, nullptr);
}

// Round 6
// 200.615 us; speedup vs baseline: 3.0889x; 1.0901x over previous
//
#include <hip/hip_runtime.h>
#include <stdint.h>
#include <stddef.h>

typedef short s8v __attribute__((ext_vector_type(8)));   // 8 bf16 (bit pattern in shorts)
typedef float f4  __attribute__((ext_vector_type(4)));
typedef float f16v __attribute__((ext_vector_type(16)));
typedef unsigned int u32;
typedef unsigned int u32x2 __attribute__((ext_vector_type(2)));
typedef unsigned int u32x4 __attribute__((ext_vector_type(4)));

#define SCALE2_ 0.18033688011112042f   /* 0.125 * log2(e) — folded into Q projection */
#define NEG_BIG -3.0e38f
#define AS1 __attribute__((address_space(1)))
#define AS3 __attribute__((address_space(3)))

static __device__ __forceinline__ short f2bf(float f) {
    u32 u = __builtin_bit_cast(u32, f);
    u = (u + 0x7fffu + ((u >> 16) & 1u)) >> 16;
    return (short)u;
}

// packed f32x2 -> bf16x2 (RNE), single HW instr (T12 primitive)
static __device__ __forceinline__ u32 cvtpk(float lo, float hi) {
    u32 r;
    asm("v_cvt_pk_bf16_f32 %0, %1, %2" : "=v"(r) : "v"(lo), "v"(hi));
    return r;
}

// ---------------- pack / convert kernels ----------------

__global__ __launch_bounds__(256) void k_cvt(const float* __restrict__ in,
                                             s8v* __restrict__ out, int n8) {
    int i = blockIdx.x * 256 + threadIdx.x;
    if (i >= n8) return;
    const float4* p = (const float4*)in;
    float4 a = p[2 * i], b = p[2 * i + 1];
    s8v o;
    o[0] = f2bf(a.x); o[1] = f2bf(a.y); o[2] = f2bf(a.z); o[3] = f2bf(a.w);
    o[4] = f2bf(b.x); o[5] = f2bf(b.y); o[6] = f2bf(b.z); o[7] = f2bf(b.w);
    out[i] = o;
}

// Wq/Wk/Wv: (16,1024,64) each -> Wqkv_bt[n][d], n = p*1024 + h*64 + k  (B^T form, N x K)
// Q weights pre-scaled by SCALE2_ (softmax scale folded into projection).
__global__ __launch_bounds__(256) void k_pack_wqkv(const float* __restrict__ Wq,
                                                   const float* __restrict__ Wk,
                                                   const float* __restrict__ Wv,
                                                   s8v* __restrict__ out) {
    int idx = blockIdx.x * 256 + threadIdx.x;   // 3072*128 threads
    int n = idx >> 7, d8 = idx & 127;
    const float* W = (n < 1024) ? Wq : ((n < 2048) ? Wk : Wv);
    const float sc = (n < 1024) ? SCALE2_ : 1.0f;
    int nn = n & 1023;
    const float* src = W + (size_t)((nn >> 6) * 1024 + d8 * 8) * 64 + (nn & 63);
    s8v o;
    #pragma unroll
    for (int i = 0; i < 8; i++) o[i] = f2bf(src[i * 64] * sc);
    out[idx] = o;
}

__global__ __launch_bounds__(256) void k_pack_bias(const float* __restrict__ bq,
                                                   const float* __restrict__ bk,
                                                   const float* __restrict__ bv,
                                                   float* __restrict__ o) {
    int n = blockIdx.x * 256 + threadIdx.x;
    if (n >= 3072) return;
    const float* b = (n < 1024) ? bq : ((n < 2048) ? bk : bv);
    o[n] = b[n & 1023] * ((n < 1024) ? SCALE2_ : 1.0f);
}

// ---------- GEMM 256x128 tile, BK=64, 3-slot counted-vmcnt pipeline (T2+T3/T4+T5) -------
// C[m][n] = A[m][:] . Bt[n][:], bf16 in. 8 waves (wm=w>>1 m-quarter, wn=w&1 n-half),
// wave tile 64x64, frag 16x16x32. LDS: 3 slots x (A 256x64 + B 128x64) = 144 KB.
// Iter kt: STAGE(kt+2) -> ds_read(kt)+MFMA -> vmcnt(6) -> s_barrier. vmcnt(6) allows only
// kt+2's 6 loads outstanding per wave => kt+1 fully landed for all waves past the barrier.
// LDS XOR-swizzle both-sides (rule 21): source chunk (l&7)^(l>>3), read chunk ^ (lr&7).
// EPI=0 (QKV, transposed: A=Wqkv m=qkv-dim, B=X n=token): Q/K packed 8B stores, V^T 2B.
// EPI=1 (out-proj: A=Ctx m=token, B=Wout n=dim): fp32 (acc+bias[n])*drop.

template <int EPI, int KDIM>
__global__ __launch_bounds__(512, 2) void gemm256(
    const short* __restrict__ A, const short* __restrict__ Bt,
    int M, int N,
    const float* __restrict__ bias,
    const float* __restrict__ drop, float* __restrict__ outf,
    short* __restrict__ outq, short* __restrict__ outk, short* __restrict__ outv)
{
    __shared__ __align__(16) short lds[73728];   // A: 3*16384, B: 3*8192 @49152
    const int tid = threadIdx.x;
    const int w = tid >> 6, l = tid & 63;
    const int wm = w >> 1, wn = w & 1;
    const int lr = l & 15, lg = l >> 4;
    const int lr3 = l >> 3, cg = (l & 7) ^ lr3;
    const int bm = blockIdx.y * 256, bn = blockIdx.x * 128;
    constexpr int NT = KDIM >> 6;

    const short* Abl = A + ((size_t)bm + lr3) * KDIM + cg * 8;
    const short* Bbl = Bt + ((size_t)bn + lr3) * KDIM + cg * 8;

    auto STAGE = [&](int kt, int s) {
        short* la = lds + s * 16384;
        short* lb = lds + 49152 + s * 8192;
        #pragma unroll
        for (int i = 0; i < 4; i++) {
            const int rg = i * 64 + w * 8;
            __builtin_amdgcn_global_load_lds(
                (const AS1 void*)(Abl + (size_t)rg * KDIM + kt * 64),
                (AS3 void*)(la + rg * 64), 16, 0, 0);
        }
        #pragma unroll
        for (int i = 0; i < 2; i++) {
            const int rg = i * 64 + w * 8;
            __builtin_amdgcn_global_load_lds(
                (const AS1 void*)(Bbl + (size_t)rg * KDIM + kt * 64),
                (AS3 void*)(lb + rg * 64), 16, 0, 0);
        }
    };

    f4 acc[4][4] = {};

    STAGE(0, 0);
    STAGE(1, 1);
    asm volatile("s_waitcnt vmcnt(6)" ::: "memory");   // tile 0 landed (all waves, pre-barrier)
    __builtin_amdgcn_s_barrier();
    __builtin_amdgcn_sched_barrier(0);

    int sr = 0;
    #pragma unroll 1
    for (int kt = 0; kt < NT; kt++) {
        if (kt + 2 < NT) STAGE(kt + 2, sr == 0 ? 2 : sr - 1);   // slot (kt+2)%3
        const short* sa = lds + sr * 16384;
        const short* sb = lds + 49152 + sr * 8192;
        #pragma unroll
        for (int c = 0; c < 2; c++) {
            s8v af[4], bfv[4];
            #pragma unroll
            for (int mt = 0; mt < 4; mt++)
                af[mt] = *(const s8v*)&sa[(wm * 64 + mt * 16 + lr) * 64
                                          + (((c * 4 + lg) ^ (lr & 7)) << 3)];
            #pragma unroll
            for (int nt = 0; nt < 4; nt++)
                bfv[nt] = *(const s8v*)&sb[(wn * 64 + nt * 16 + lr) * 64
                                           + (((c * 4 + lg) ^ (lr & 7)) << 3)];
            __builtin_amdgcn_s_setprio(1);
            #pragma unroll
            for (int mt = 0; mt < 4; mt++)
                #pragma unroll
                for (int nt = 0; nt < 4; nt++)
                    acc[mt][nt] = __builtin_amdgcn_mfma_f32_16x16x32_bf16(
                        af[mt], bfv[nt], acc[mt][nt], 0, 0, 0);
            __builtin_amdgcn_s_setprio(0);
        }
        if (kt < NT - 1) {
            if (kt < NT - 2) asm volatile("s_waitcnt vmcnt(6)" ::: "memory");
            else             asm volatile("s_waitcnt vmcnt(0)" ::: "memory");
            __builtin_amdgcn_s_barrier();
            __builtin_amdgcn_sched_barrier(0);
        }
        sr = (sr == 2) ? 0 : sr + 1;
    }

    if (EPI == 0) {
        // m = qkv-dim (p,hh,kk), n = token. p constant per block (256 | 1024).
        const int pq = bm >> 10;
        #pragma unroll
        for (int mt = 0; mt < 4; mt++) {
            const int m0 = bm + wm * 64 + mt * 16 + lg * 4;
            const float4 bb = *(const float4*)&bias[m0];
            const int hh = (m0 >> 6) & 15, kk0 = m0 & 63;
            #pragma unroll
            for (int nt = 0; nt < 4; nt++) {
                const int n = bn + wn * 64 + nt * 16 + lr;
                const int b = n >> 11, t = n & 2047;
                const size_t bh = (size_t)(b * 16 + hh);
                const float v0 = acc[mt][nt][0] + bb.x, v1 = acc[mt][nt][1] + bb.y;
                const float v2 = acc[mt][nt][2] + bb.z, v3 = acc[mt][nt][3] + bb.w;
                if (pq == 2) {          // V^T[bh][kk][t]
                    short* d = outv + bh * 131072 + (size_t)kk0 * 2048 + t;
                    d[0] = f2bf(v0); d[2048] = f2bf(v1);
                    d[4096] = f2bf(v2); d[6144] = f2bf(v3);
                } else {                // Q/K[bh][t][kk0..kk0+3] packed 8B
                    short* d = ((pq == 0) ? outq : outk) + (bh * 2048 + t) * 64 + kk0;
                    u32x2 pr = {cvtpk(v0, v1), cvtpk(v2, v3)};
                    *(u32x2*)d = pr;
                }
            }
        }
    } else {
        // m = token row, n = out-dim
        #pragma unroll
        for (int mt = 0; mt < 4; mt++) {
            const int m0 = bm + wm * 64 + mt * 16 + lg * 4;
            #pragma unroll
            for (int nt = 0; nt < 4; nt++) {
                const int n = bn + wn * 64 + nt * 16 + lr;
                const float bb = bias[n];
                #pragma unroll
                for (int j = 0; j < 4; j++) {
                    const size_t off = (size_t)(m0 + j) * N + n;
                    outf[off] = (acc[mt][nt][j] + bb) * drop[off];
                }
            }
        }
    }
}

// ---------------- flash attention (causal, 32x32 MFMA, in-register softmax) --------------
// Q (pre-scaled),K: bf16 [bh][t][64]. Vt: bf16 [bh][v][t]. Ctx: bf16 [bh][t][64].
// Block = 4 waves x 32 q-rows = 128 q-rows. Pairing (15-p, p) -> 34 kv-iters, balanced.
// K and V^T tiles (64x64) double-buffered in LDS via global_load_lds + XOR chunk swizzle.
// Swapped QK^T (mfma_32x32x16: S^T[key][q], col=lane&31=q) -> lane owns a full half-row;
// softmax in-register; P->B-fragment via 16 cvt_pk + 8 permlane32_swap (T12).

__global__ __launch_bounds__(256, 2) void attn_fwd(
    const short* __restrict__ Q, const short* __restrict__ Kv,
    const short* __restrict__ Vt, short* __restrict__ Ctx)
{
    const int i = blockIdx.x;                    // 0..511
    const int bh = (i & 7) * 8 + ((i >> 3) & 7); // 8 blocks of a bh on one XCD (T1)
    const int p = i >> 6;                        // 0..7
    const int tid = threadIdx.x, w = tid >> 6, l = tid & 63;
    const int lq = l & 31, hh = l >> 5;

    __shared__ short KbA[64 * 64], KbB[64 * 64];   // 8 KB each
    __shared__ short VbA[64 * 64], VbB[64 * 64];
    __shared__ short Ol[4][32][72];                // per-wave O transpose buffer

    const size_t base = (size_t)bh * 131072;
    const short* Kg = Kv + base;
    const short* Vg = Vt + base;

    // stage kv-tile j: LDS[row][c] = global[row][c ^ (row&7)]  (16B chunks, rule #21)
    auto stage = [&](int j, short* kb, short* vb) {
        const int cg = (l & 7) ^ (l >> 3);
        #pragma unroll
        for (int i2 = 0; i2 < 2; i2++) {
            const int r2 = w * 16 + i2 * 8 + (l >> 3);
            __builtin_amdgcn_global_load_lds(
                (const AS1 void*)(Kg + (size_t)(j * 64 + r2) * 64 + cg * 8),
                (AS3 void*)(kb + (w * 16 + i2 * 8) * 64), 16, 0, 0);
            __builtin_amdgcn_global_load_lds(
                (const AS1 void*)(Vg + (size_t)r2 * 2048 + j * 64 + cg * 8),
                (AS3 void*)(vb + (w * 16 + i2 * 8) * 64), 16, 0, 0);
        }
    };

    auto run_tile = [&](const int qb) {
        const int nj = 2 * qb + 2;
        const int qt0 = qb * 128 + w * 32;
        const int qrow = qt0 + lq;

        s8v qf[4];
        #pragma unroll
        for (int m = 0; m < 4; m++)
            qf[m] = *(const s8v*)&Q[base + (size_t)(qt0 + lq) * 64 + m * 16 + hh * 8];

        f16v acc0 = {}, acc1 = {};            // v rows 0..31 / 32..63 (col=q)
        float m_run = NEG_BIG, l_run = 0.f;

        stage(0, KbA, VbA);

        for (int j = 0; j < nj; j++) {
            __syncthreads();                  // stage(j) drained; prev reads done
            short* kb = (j & 1) ? KbB : KbA;
            short* vb = (j & 1) ? VbB : VbA;
            if (j + 1 < nj) stage(j + 1, (j & 1) ? KbA : KbB, (j & 1) ? VbA : VbB);

            if (64 * j > qt0 + 31) continue;  // fully masked for this wave

            // S^T = K * Q^T  (two 32-key halves, K from LDS, swizzled reads)
            f16v sA = {}, sB = {};
            #pragma unroll
            for (int m = 0; m < 4; m++) {
                const int ck = ((2 * m + hh) ^ (l & 7)) * 8;
                const s8v ka = *(const s8v*)&kb[lq * 64 + ck];
                const s8v kc = *(const s8v*)&kb[(32 + lq) * 64 + ck];
                sA = __builtin_amdgcn_mfma_f32_32x32x16_bf16(ka, qf[m], sA, 0, 0, 0);
                sB = __builtin_amdgcn_mfma_f32_32x32x16_bf16(kc, qf[m], sB, 0, 0, 0);
            }

            // causal mask on boundary tiles (wave-uniform branch)
            if (64 * j + 63 > qt0) {
                #pragma unroll
                for (int r = 0; r < 16; r++) {
                    const int klo = 64 * j + (r & 3) + 8 * (r >> 2) + 4 * hh;
                    if (klo > qrow)      sA[r] = NEG_BIG;
                    if (klo + 32 > qrow) sB[r] = NEG_BIG;
                }
            }

            // in-register row max (lane's 32 values, one q) + half-row combine
            float mx[8];
            #pragma unroll
            for (int r = 0; r < 8; r++)
                mx[r] = fmaxf(fmaxf(sA[r], sA[r + 8]), fmaxf(sB[r], sB[r + 8]));
            float pm = fmaxf(fmaxf(fmaxf(mx[0], mx[1]), fmaxf(mx[2], mx[3])),
                             fmaxf(fmaxf(mx[4], mx[5]), fmaxf(mx[6], mx[7])));
            pm = fmaxf(pm, __shfl_xor(pm, 32));

            // defer-max (T13, THR=8 in exp2 domain)
            if (!__all(pm <= m_run + 8.f)) {
                const float m_new = fmaxf(m_run, pm);
                const float so = exp2f(m_run - m_new);
                l_run *= so;
                #pragma unroll
                for (int r = 0; r < 16; r++) { acc0[r] *= so; acc1[r] *= so; }
                m_run = m_new;
            }

            // exp2 in place + row sum
            #pragma unroll
            for (int r = 0; r < 16; r++) {
                sA[r] = exp2f(sA[r] - m_run);
                sB[r] = exp2f(sB[r] - m_run);
            }
            float sm[8];
            #pragma unroll
            for (int r = 0; r < 8; r++)
                sm[r] = (sA[r] + sA[r + 8]) + (sB[r] + sB[r + 8]);
            float ps = ((sm[0] + sm[1]) + (sm[2] + sm[3])) +
                       ((sm[4] + sm[5]) + (sm[6] + sm[7]));
            ps += __shfl_xor(ps, 32);
            l_run += ps;

            // P fragments (cvt_pk + permlane32_swap) + PV accumulate
            #pragma unroll
            for (int m = 0; m < 4; m++) {
                const int rb = (m & 1) * 8;
                u32 P0, P1, P2, P3;
                if (m < 2) {
                    P0 = cvtpk(sA[rb + 0], sA[rb + 1]); P1 = cvtpk(sA[rb + 2], sA[rb + 3]);
                    P2 = cvtpk(sA[rb + 4], sA[rb + 5]); P3 = cvtpk(sA[rb + 6], sA[rb + 7]);
                } else {
                    P0 = cvtpk(sB[rb + 0], sB[rb + 1]); P1 = cvtpk(sB[rb + 2], sB[rb + 3]);
                    P2 = cvtpk(sB[rb + 4], sB[rb + 5]); P3 = cvtpk(sB[rb + 6], sB[rb + 7]);
                }
                const u32x2 s02 = __builtin_amdgcn_permlane32_swap(P0, P2, false, false);
                const u32x2 s13 = __builtin_amdgcn_permlane32_swap(P1, P3, false, false);
                const u32x4 uv = {s02[0], s13[0], s02[1], s13[1]};
                const s8v pf = __builtin_bit_cast(s8v, uv);

                const int ck = ((2 * m + hh) ^ (l & 7)) * 8;
                const s8v va = *(const s8v*)&vb[lq * 64 + ck];
                const s8v vc = *(const s8v*)&vb[(32 + lq) * 64 + ck];
                acc0 = __builtin_amdgcn_mfma_f32_32x32x16_bf16(va, pf, acc0, 0, 0, 0);
                acc1 = __builtin_amdgcn_mfma_f32_32x32x16_bf16(vc, pf, acc1, 0, 0, 0);
            }
        }

        // epilogue: normalize, per-wave LDS transpose, coalesced bf16 store
        const float inv = 1.f / l_run;
        #pragma unroll
        for (int r = 0; r < 16; r += 2) {
            const int v0 = (r & 3) + 8 * (r >> 2) + 4 * hh;
            *(u32*)&Ol[w][lq][v0]      = cvtpk(acc0[r] * inv, acc0[r + 1] * inv);
            *(u32*)&Ol[w][lq][32 + v0] = cvtpk(acc1[r] * inv, acc1[r + 1] * inv);
        }
        #pragma unroll
        for (int c = 0; c < 4; c++) {
            const s8v o = *(const s8v*)&Ol[w][l >> 1][(l & 1) * 32 + c * 8];
            *(s8v*)&Ctx[base + (size_t)(qt0 + (l >> 1)) * 64 + (l & 1) * 32 + c * 8] = o;
        }
    };

    run_tile(15 - p);
    __syncthreads();        // protect LDS buffers across tiles
    run_tile(p);
}

// ---------------- launch ----------------

#define WS_XB   ((size_t)0)
#define WS_WQKV ((size_t)16777216)
#define WS_WOUT ((size_t)23068672)
#define WS_BQKV ((size_t)25165824)
#define WS_Q    ((size_t)25178112)
#define WS_K    ((size_t)41955328)
#define WS_V    ((size_t)58732544)
#define WS_CTX  ((size_t)75509760)

extern "C" void kernel_launch(void* const* d_in, const int* in_sizes, int n_in,
                              void* d_out, int out_size, void* d_ws, size_t ws_size,
                              hipStream_t stream) {
    const float* x    = (const float*)d_in[0];
    // d_in[1] = attn_mask (causal, hardcoded in attn_fwd)
    const float* Wq   = (const float*)d_in[2];
    const float* bq   = (const float*)d_in[3];
    const float* Wk   = (const float*)d_in[4];
    const float* bk   = (const float*)d_in[5];
    const float* Wv   = (const float*)d_in[6];
    const float* bv   = (const float*)d_in[7];
    const float* Wout = (const float*)d_in[8];
    const float* bout = (const float*)d_in[9];
    const float* drop = (const float*)d_in[10];
    float* out = (float*)d_out;

    char* ws = (char*)d_ws;
    short* Xb    = (short*)(ws + WS_XB);
    short* Wqkvb = (short*)(ws + WS_WQKV);
    short* Woutb = (short*)(ws + WS_WOUT);
    float* bqkv  = (float*)(ws + WS_BQKV);
    short* Qb    = (short*)(ws + WS_Q);
    short* Kb    = (short*)(ws + WS_K);
    short* Vtb   = (short*)(ws + WS_V);     // V stored TRANSPOSED: [bh][v][t]
    short* Ctxb  = (short*)(ws + WS_CTX);

    k_cvt<<<4096, 256, 0, stream>>>(x, (s8v*)Xb, 1048576);          // x -> bf16
    k_cvt<<<512, 256, 0, stream>>>(Wout, (s8v*)Woutb, 131072);      // Wout -> bf16 (B^T form)
    k_pack_wqkv<<<1536, 256, 0, stream>>>(Wq, Wk, Wv, (s8v*)Wqkvb);
    k_pack_bias<<<12, 256, 0, stream>>>(bq, bk, bv, bqkv);

    // QKV projection, transposed orientation: A=Wqkv (M=3072), B=X (N=8192 tokens)
    gemm256<0, 1024><<<dim3(64, 12), 512, 0, stream>>>(
        Wqkvb, Xb, 3072, 8192, bqkv, nullptr, nullptr, Qb, Kb, Vtb);

    attn_fwd<<<dim3(512), 256, 0, stream>>>(Qb, Kb, Vtb, Ctxb);

    // output projection: A=Ctx (M=8192 tokens), B=Wout (N=1024)
    gemm256<1, 1024><<<dim3(8, 32), 512, 0, stream>>>(
        Ctxb, Woutb, 8192, 1024, bout, drop, out, nullptr, nullptr, nullptr);
}

// Round 7
// 195.139 us; speedup vs baseline: 3.1756x; 1.0281x over previous
//
#include <hip/hip_runtime.h>
#include <stdint.h>
#include <stddef.h>

typedef short s8v __attribute__((ext_vector_type(8)));   // 8 bf16 (bit pattern in shorts)
typedef float f4  __attribute__((ext_vector_type(4)));
typedef float f16v __attribute__((ext_vector_type(16)));
typedef unsigned int u32;
typedef unsigned int u32x2 __attribute__((ext_vector_type(2)));
typedef unsigned int u32x4 __attribute__((ext_vector_type(4)));

#define SCALE2_ 0.18033688011112042f   /* 0.125 * log2(e) — folded into Q projection */
#define NEG_BIG -3.0e38f
#define AS1 __attribute__((address_space(1)))
#define AS3 __attribute__((address_space(3)))

static __device__ __forceinline__ short f2bf(float f) {
    u32 u = __builtin_bit_cast(u32, f);
    u = (u + 0x7fffu + ((u >> 16) & 1u)) >> 16;
    return (short)u;
}

// packed f32x2 -> bf16x2 (RNE), single HW instr (T12 primitive)
static __device__ __forceinline__ u32 cvtpk(float lo, float hi) {
    u32 r;
    asm("v_cvt_pk_bf16_f32 %0, %1, %2" : "=v"(r) : "v"(lo), "v"(hi));
    return r;
}

// ---------------- pack / convert kernels ----------------

__global__ __launch_bounds__(256) void k_cvt(const float* __restrict__ in,
                                             s8v* __restrict__ out, int n8) {
    int i = blockIdx.x * 256 + threadIdx.x;
    if (i >= n8) return;
    const float4* p = (const float4*)in;
    float4 a = p[2 * i], b = p[2 * i + 1];
    s8v o;
    o[0] = f2bf(a.x); o[1] = f2bf(a.y); o[2] = f2bf(a.z); o[3] = f2bf(a.w);
    o[4] = f2bf(b.x); o[5] = f2bf(b.y); o[6] = f2bf(b.z); o[7] = f2bf(b.w);
    out[i] = o;
}

// Wq/Wk/Wv: (16,1024,64) each -> Wqkv_bt[n][d], n = p*1024 + h*64 + k  (B^T form, N x K)
// Q weights pre-scaled by SCALE2_ (softmax scale folded into projection).
__global__ __launch_bounds__(256) void k_pack_wqkv(const float* __restrict__ Wq,
                                                   const float* __restrict__ Wk,
                                                   const float* __restrict__ Wv,
                                                   s8v* __restrict__ out) {
    int idx = blockIdx.x * 256 + threadIdx.x;   // 3072*128 threads
    int n = idx >> 7, d8 = idx & 127;
    const float* W = (n < 1024) ? Wq : ((n < 2048) ? Wk : Wv);
    const float sc = (n < 1024) ? SCALE2_ : 1.0f;
    int nn = n & 1023;
    const float* src = W + (size_t)((nn >> 6) * 1024 + d8 * 8) * 64 + (nn & 63);
    s8v o;
    #pragma unroll
    for (int i = 0; i < 8; i++) o[i] = f2bf(src[i * 64] * sc);
    out[idx] = o;
}

__global__ __launch_bounds__(256) void k_pack_bias(const float* __restrict__ bq,
                                                   const float* __restrict__ bk,
                                                   const float* __restrict__ bv,
                                                   float* __restrict__ o) {
    int n = blockIdx.x * 256 + threadIdx.x;
    if (n >= 3072) return;
    const float* b = (n < 1024) ? bq : ((n < 2048) ? bk : bv);
    o[n] = b[n & 1023] * ((n < 1024) ? SCALE2_ : 1.0f);
}

// ---------- GEMM 256x128 tile, BK=64, 3-slot counted-vmcnt pipeline (T2+T3/T4+T5) -------

template <int EPI, int KDIM>
__global__ __launch_bounds__(512, 2) void gemm256(
    const short* __restrict__ A, const short* __restrict__ Bt,
    int M, int N,
    const float* __restrict__ bias,
    const float* __restrict__ drop, float* __restrict__ outf,
    short* __restrict__ outq, short* __restrict__ outk, short* __restrict__ outv)
{
    __shared__ __align__(16) short lds[73728];   // A: 3*16384, B: 3*8192 @49152
    const int tid = threadIdx.x;
    const int w = tid >> 6, l = tid & 63;
    const int wm = w >> 1, wn = w & 1;
    const int lr = l & 15, lg = l >> 4;
    const int lr3 = l >> 3, cg = (l & 7) ^ lr3;
    const int bm = blockIdx.y * 256, bn = blockIdx.x * 128;
    constexpr int NT = KDIM >> 6;

    const short* Abl = A + ((size_t)bm + lr3) * KDIM + cg * 8;
    const short* Bbl = Bt + ((size_t)bn + lr3) * KDIM + cg * 8;

    auto STAGE = [&](int kt, int s) {
        short* la = lds + s * 16384;
        short* lb = lds + 49152 + s * 8192;
        #pragma unroll
        for (int i = 0; i < 4; i++) {
            const int rg = i * 64 + w * 8;
            __builtin_amdgcn_global_load_lds(
                (const AS1 void*)(Abl + (size_t)rg * KDIM + kt * 64),
                (AS3 void*)(la + rg * 64), 16, 0, 0);
        }
        #pragma unroll
        for (int i = 0; i < 2; i++) {
            const int rg = i * 64 + w * 8;
            __builtin_amdgcn_global_load_lds(
                (const AS1 void*)(Bbl + (size_t)rg * KDIM + kt * 64),
                (AS3 void*)(lb + rg * 64), 16, 0, 0);
        }
    };

    f4 acc[4][4] = {};

    STAGE(0, 0);
    STAGE(1, 1);
    asm volatile("s_waitcnt vmcnt(6)" ::: "memory");   // tile 0 landed (all waves, pre-barrier)
    __builtin_amdgcn_s_barrier();
    __builtin_amdgcn_sched_barrier(0);

    int sr = 0;
    #pragma unroll 1
    for (int kt = 0; kt < NT; kt++) {
        if (kt + 2 < NT) STAGE(kt + 2, sr == 0 ? 2 : sr - 1);   // slot (kt+2)%3
        const short* sa = lds + sr * 16384;
        const short* sb = lds + 49152 + sr * 8192;
        #pragma unroll
        for (int c = 0; c < 2; c++) {
            s8v af[4], bfv[4];
            #pragma unroll
            for (int mt = 0; mt < 4; mt++)
                af[mt] = *(const s8v*)&sa[(wm * 64 + mt * 16 + lr) * 64
                                          + (((c * 4 + lg) ^ (lr & 7)) << 3)];
            #pragma unroll
            for (int nt = 0; nt < 4; nt++)
                bfv[nt] = *(const s8v*)&sb[(wn * 64 + nt * 16 + lr) * 64
                                           + (((c * 4 + lg) ^ (lr & 7)) << 3)];
            __builtin_amdgcn_s_setprio(1);
            #pragma unroll
            for (int mt = 0; mt < 4; mt++)
                #pragma unroll
                for (int nt = 0; nt < 4; nt++)
                    acc[mt][nt] = __builtin_amdgcn_mfma_f32_16x16x32_bf16(
                        af[mt], bfv[nt], acc[mt][nt], 0, 0, 0);
            __builtin_amdgcn_s_setprio(0);
        }
        if (kt < NT - 1) {
            if (kt < NT - 2) asm volatile("s_waitcnt vmcnt(6)" ::: "memory");
            else             asm volatile("s_waitcnt vmcnt(0)" ::: "memory");
            __builtin_amdgcn_s_barrier();
            __builtin_amdgcn_sched_barrier(0);
        }
        sr = (sr == 2) ? 0 : sr + 1;
    }

    if (EPI == 0) {
        // m = qkv-dim (p,hh,kk), n = token. p constant per block (256 | 1024).
        const int pq = bm >> 10;
        #pragma unroll
        for (int mt = 0; mt < 4; mt++) {
            const int m0 = bm + wm * 64 + mt * 16 + lg * 4;
            const float4 bb = *(const float4*)&bias[m0];
            const int hh = (m0 >> 6) & 15, kk0 = m0 & 63;
            #pragma unroll
            for (int nt = 0; nt < 4; nt++) {
                const int n = bn + wn * 64 + nt * 16 + lr;
                const int b = n >> 11, t = n & 2047;
                const size_t bh = (size_t)(b * 16 + hh);
                const float v0 = acc[mt][nt][0] + bb.x, v1 = acc[mt][nt][1] + bb.y;
                const float v2 = acc[mt][nt][2] + bb.z, v3 = acc[mt][nt][3] + bb.w;
                if (pq == 2) {          // V^T[bh][kk][t]
                    short* d = outv + bh * 131072 + (size_t)kk0 * 2048 + t;
                    d[0] = f2bf(v0); d[2048] = f2bf(v1);
                    d[4096] = f2bf(v2); d[6144] = f2bf(v3);
                } else {                // Q/K[bh][t][kk0..kk0+3] packed 8B
                    short* d = ((pq == 0) ? outq : outk) + (bh * 2048 + t) * 64 + kk0;
                    u32x2 pr = {cvtpk(v0, v1), cvtpk(v2, v3)};
                    *(u32x2*)d = pr;
                }
            }
        }
    } else {
        // m = token row, n = out-dim
        #pragma unroll
        for (int mt = 0; mt < 4; mt++) {
            const int m0 = bm + wm * 64 + mt * 16 + lg * 4;
            #pragma unroll
            for (int nt = 0; nt < 4; nt++) {
                const int n = bn + wn * 64 + nt * 16 + lr;
                const float bb = bias[n];
                #pragma unroll
                for (int j = 0; j < 4; j++) {
                    const size_t off = (size_t)(m0 + j) * N + n;
                    outf[off] = (acc[mt][nt][j] + bb) * drop[off];
                }
            }
        }
    }
}

// ---------------- flash attention (causal, 32x32 MFMA, in-register softmax) --------------
// Q (pre-scaled),K: bf16 [bh][t][64]. Vt: bf16 [bh][v][t]. Ctx: bf16 [bh][t][64].
// 1024 blocks: one 128-q-row tile each (4 waves x 32 rows), big tiles dispatched first,
// XCD-grouped (blocks of a bh stay on one XCD -> K/V L2-resident). 32 KB LDS (K+V dbuf
// via global_load_lds + XOR chunk swizzle, rule 21); O-transpose reuses the same LDS.
// Swapped QK^T (mfma_32x32x16: S^T[key][q], col=lane&31=q) -> lane owns a full half-row;
// softmax in-register; P->B-fragment via 16 cvt_pk + 8 permlane32_swap (T12).

__global__ __launch_bounds__(256, 4) void attn_fwd(
    const short* __restrict__ Q, const short* __restrict__ Kv,
    const short* __restrict__ Vt, short* __restrict__ Ctx)
{
    const int i = blockIdx.x;                    // 0..1023
    const int bh = (i & 7) * 8 + ((i >> 3) & 7); // 16 blocks of a bh on one XCD (T1)
    const int qb = 15 - (i >> 6);                // big tiles first
    const int tid = threadIdx.x, w = tid >> 6, l = tid & 63;
    const int lq = l & 31, hh = l >> 5;

    __shared__ short smem[16384];                // 32 KB: K dbuf [0,8K), V dbuf [8K,16K)

    const size_t base = (size_t)bh * 131072;
    const short* Kg = Kv + base;
    const short* Vg = Vt + base;

    // stage kv-tile j: LDS[row][c] = global[row][c ^ (row&7)]  (16B chunks, rule #21)
    auto stage = [&](int j) {
        short* kb = smem + (j & 1) * 4096;
        short* vb = smem + 8192 + (j & 1) * 4096;
        const int cg = (l & 7) ^ (l >> 3);
        #pragma unroll
        for (int i2 = 0; i2 < 2; i2++) {
            const int r2 = w * 16 + i2 * 8 + (l >> 3);
            __builtin_amdgcn_global_load_lds(
                (const AS1 void*)(Kg + (size_t)(j * 64 + r2) * 64 + cg * 8),
                (AS3 void*)(kb + (w * 16 + i2 * 8) * 64), 16, 0, 0);
            __builtin_amdgcn_global_load_lds(
                (const AS1 void*)(Vg + (size_t)r2 * 2048 + j * 64 + cg * 8),
                (AS3 void*)(vb + (w * 16 + i2 * 8) * 64), 16, 0, 0);
        }
    };

    const int nj = 2 * qb + 2;
    const int qt0 = qb * 128 + w * 32;
    const int qrow = qt0 + lq;

    s8v qf[4];
    #pragma unroll
    for (int m = 0; m < 4; m++)
        qf[m] = *(const s8v*)&Q[base + (size_t)(qt0 + lq) * 64 + m * 16 + hh * 8];

    f16v acc0 = {}, acc1 = {};            // v rows 0..31 / 32..63 (col=q)
    float m_run = NEG_BIG, l_run = 0.f;

    stage(0);

    for (int j = 0; j < nj; j++) {
        __syncthreads();                  // stage(j) drained; prev reads done
        const short* kb = smem + (j & 1) * 4096;
        const short* vb = smem + 8192 + (j & 1) * 4096;
        if (j + 1 < nj) stage(j + 1);

        if (64 * j > qt0 + 31) continue;  // fully masked for this wave (w=0 last iter)

        // S^T = K * Q^T  (two 32-key halves, K from LDS, swizzled reads)
        f16v sA = {}, sB = {};
        #pragma unroll
        for (int m = 0; m < 4; m++) {
            const int ck = ((2 * m + hh) ^ (l & 7)) * 8;
            const s8v ka = *(const s8v*)&kb[lq * 64 + ck];
            const s8v kc = *(const s8v*)&kb[(32 + lq) * 64 + ck];
            sA = __builtin_amdgcn_mfma_f32_32x32x16_bf16(ka, qf[m], sA, 0, 0, 0);
            sB = __builtin_amdgcn_mfma_f32_32x32x16_bf16(kc, qf[m], sB, 0, 0, 0);
        }

        // causal mask on boundary tiles (wave-uniform branch)
        if (64 * j + 63 > qt0) {
            #pragma unroll
            for (int r = 0; r < 16; r++) {
                const int klo = 64 * j + (r & 3) + 8 * (r >> 2) + 4 * hh;
                if (klo > qrow)      sA[r] = NEG_BIG;
                if (klo + 32 > qrow) sB[r] = NEG_BIG;
            }
        }

        // in-register row max (lane's 32 values, one q) + half-row combine
        float mx[8];
        #pragma unroll
        for (int r = 0; r < 8; r++)
            mx[r] = fmaxf(fmaxf(sA[r], sA[r + 8]), fmaxf(sB[r], sB[r + 8]));
        float pm = fmaxf(fmaxf(fmaxf(mx[0], mx[1]), fmaxf(mx[2], mx[3])),
                         fmaxf(fmaxf(mx[4], mx[5]), fmaxf(mx[6], mx[7])));
        pm = fmaxf(pm, __shfl_xor(pm, 32));

        // defer-max (T13, THR=8 in exp2 domain)
        if (!__all(pm <= m_run + 8.f)) {
            const float m_new = fmaxf(m_run, pm);
            const float so = exp2f(m_run - m_new);
            l_run *= so;
            #pragma unroll
            for (int r = 0; r < 16; r++) { acc0[r] *= so; acc1[r] *= so; }
            m_run = m_new;
        }

        // exp2 in place + row sum
        #pragma unroll
        for (int r = 0; r < 16; r++) {
            sA[r] = exp2f(sA[r] - m_run);
            sB[r] = exp2f(sB[r] - m_run);
        }
        float sm[8];
        #pragma unroll
        for (int r = 0; r < 8; r++)
            sm[r] = (sA[r] + sA[r + 8]) + (sB[r] + sB[r + 8]);
        float ps = ((sm[0] + sm[1]) + (sm[2] + sm[3])) +
                   ((sm[4] + sm[5]) + (sm[6] + sm[7]));
        ps += __shfl_xor(ps, 32);
        l_run += ps;

        // P fragments (cvt_pk + permlane32_swap) + PV accumulate
        #pragma unroll
        for (int m = 0; m < 4; m++) {
            const int rb = (m & 1) * 8;
            u32 P0, P1, P2, P3;
            if (m < 2) {
                P0 = cvtpk(sA[rb + 0], sA[rb + 1]); P1 = cvtpk(sA[rb + 2], sA[rb + 3]);
                P2 = cvtpk(sA[rb + 4], sA[rb + 5]); P3 = cvtpk(sA[rb + 6], sA[rb + 7]);
            } else {
                P0 = cvtpk(sB[rb + 0], sB[rb + 1]); P1 = cvtpk(sB[rb + 2], sB[rb + 3]);
                P2 = cvtpk(sB[rb + 4], sB[rb + 5]); P3 = cvtpk(sB[rb + 6], sB[rb + 7]);
            }
            const u32x2 s02 = __builtin_amdgcn_permlane32_swap(P0, P2, false, false);
            const u32x2 s13 = __builtin_amdgcn_permlane32_swap(P1, P3, false, false);
            const u32x4 uv = {s02[0], s13[0], s02[1], s13[1]};
            const s8v pf = __builtin_bit_cast(s8v, uv);

            const int ck = ((2 * m + hh) ^ (l & 7)) * 8;
            const s8v va = *(const s8v*)&vb[lq * 64 + ck];
            const s8v vc = *(const s8v*)&vb[(32 + lq) * 64 + ck];
            acc0 = __builtin_amdgcn_mfma_f32_32x32x16_bf16(va, pf, acc0, 0, 0, 0);
            acc1 = __builtin_amdgcn_mfma_f32_32x32x16_bf16(vc, pf, acc1, 0, 0, 0);
        }
    }

    // epilogue: normalize, transpose via LDS scratch (reuse K/V region), bf16 store
    __syncthreads();                        // all waves done reading K/V buffers
    {
        short* Os = smem + w * 2176;        // per-wave 32 rows x 68-short stride
        const float inv = 1.f / l_run;
        #pragma unroll
        for (int r = 0; r < 16; r += 2) {
            const int v0 = (r & 3) + 8 * (r >> 2) + 4 * hh;
            *(u32*)&Os[lq * 68 + v0]      = cvtpk(acc0[r] * inv, acc0[r + 1] * inv);
            *(u32*)&Os[lq * 68 + 32 + v0] = cvtpk(acc1[r] * inv, acc1[r + 1] * inv);
        }
        // wave-synchronous read-back (same wave wrote it)
        #pragma unroll
        for (int c = 0; c < 4; c++) {
            const s8v o = *(const s8v*)&Os[(l >> 1) * 68 + (l & 1) * 32 + c * 8];
            *(s8v*)&Ctx[base + (size_t)(qt0 + (l >> 1)) * 64 + (l & 1) * 32 + c * 8] = o;
        }
    }
}

// ---------------- launch ----------------

#define WS_XB   ((size_t)0)
#define WS_WQKV ((size_t)16777216)
#define WS_WOUT ((size_t)23068672)
#define WS_BQKV ((size_t)25165824)
#define WS_Q    ((size_t)25178112)
#define WS_K    ((size_t)41955328)
#define WS_V    ((size_t)58732544)
#define WS_CTX  ((size_t)75509760)

extern "C" void kernel_launch(void* const* d_in, const int* in_sizes, int n_in,
                              void* d_out, int out_size, void* d_ws, size_t ws_size,
                              hipStream_t stream) {
    const float* x    = (const float*)d_in[0];
    // d_in[1] = attn_mask (causal, hardcoded in attn_fwd)
    const float* Wq   = (const float*)d_in[2];
    const float* bq   = (const float*)d_in[3];
    const float* Wk   = (const float*)d_in[4];
    const float* bk   = (const float*)d_in[5];
    const float* Wv   = (const float*)d_in[6];
    const float* bv   = (const float*)d_in[7];
    const float* Wout = (const float*)d_in[8];
    const float* bout = (const float*)d_in[9];
    const float* drop = (const float*)d_in[10];
    float* out = (float*)d_out;

    char* ws = (char*)d_ws;
    short* Xb    = (short*)(ws + WS_XB);
    short* Wqkvb = (short*)(ws + WS_WQKV);
    short* Woutb = (short*)(ws + WS_WOUT);
    float* bqkv  = (float*)(ws + WS_BQKV);
    short* Qb    = (short*)(ws + WS_Q);
    short* Kb    = (short*)(ws + WS_K);
    short* Vtb   = (short*)(ws + WS_V);     // V stored TRANSPOSED: [bh][v][t]
    short* Ctxb  = (short*)(ws + WS_CTX);

    k_cvt<<<4096, 256, 0, stream>>>(x, (s8v*)Xb, 1048576);          // x -> bf16
    k_cvt<<<512, 256, 0, stream>>>(Wout, (s8v*)Woutb, 131072);      // Wout -> bf16 (B^T form)
    k_pack_wqkv<<<1536, 256, 0, stream>>>(Wq, Wk, Wv, (s8v*)Wqkvb);
    k_pack_bias<<<12, 256, 0, stream>>>(bq, bk, bv, bqkv);

    // QKV projection, transposed orientation: A=Wqkv (M=3072), B=X (N=8192 tokens)
    gemm256<0, 1024><<<dim3(64, 12), 512, 0, stream>>>(
        Wqkvb, Xb, 3072, 8192, bqkv, nullptr, nullptr, Qb, Kb, Vtb);

    attn_fwd<<<dim3(1024), 256, 0, stream>>>(Qb, Kb, Vtb, Ctxb);

    // output projection: A=Ctx (M=8192 tokens), B=Wout (N=1024)
    gemm256<1, 1024><<<dim3(8, 32), 512, 0, stream>>>(
        Ctxb, Woutb, 8192, 1024, bout, drop, out, nullptr, nullptr, nullptr);
}